// Round 12
// baseline (261.940 us; speedup 1.0000x reference)
//
#include <hip/hip_runtime.h>
#include <hip/hip_bf16.h>
#include <cstring>

#define BB 16
#define LL 2048
#define DD 256
#define NN 16
#define RR 16
// fused path: 32 chunks of 64 rows. fallback path: 64 chunks of 32 rows.
#define CHF 32
#define LCF 64
#define CHB 64
#define LCB 32

static __device__ __forceinline__ float bf2f(unsigned short u) {
    return __uint_as_float(((unsigned)u) << 16);
}
static __device__ __forceinline__ unsigned short f2bf(float f) {
    unsigned u = __float_as_uint(f);
    u += 0x7FFFu + ((u >> 16) & 1u);
    return (unsigned short)(u >> 16);
}

typedef __attribute__((ext_vector_type(8))) short bf16x8;
typedef __attribute__((ext_vector_type(4))) short bf16x4;
typedef __attribute__((ext_vector_type(4))) float f32x4;

// e[n] = E^(n+1), depth-4 product tree
static __device__ __forceinline__ void pow_tree(float E, float* e) {
    e[0] = E;
    e[1] = E * E;
    e[2] = e[1] * E;
    e[3] = e[1] * e[1];
    e[4] = e[3] * e[0];  e[5] = e[3] * e[1];  e[6] = e[3] * e[2];  e[7] = e[3] * e[3];
    e[8] = e[7] * e[0];  e[9] = e[7] * e[1];  e[10] = e[7] * e[2]; e[11] = e[7] * e[3];
    e[12] = e[7] * e[4]; e[13] = e[7] * e[5]; e[14] = e[7] * e[6]; e[15] = e[7] * e[7];
}

// Device-scope grid barrier (generation counting). Requires all blocks
// resident (guaranteed by __launch_bounds__(256,2) + gate). cnt=bar[0], gen=bar[32].
static __device__ __forceinline__ void gridBarrier(unsigned* bar, unsigned nblk) {
    __threadfence();            // release: my stores visible device-scope
    __syncthreads();
    if (threadIdx.x == 0) {
        unsigned* cnt = bar;
        unsigned* gen = bar + 32;
        const unsigned gsnap = atomicAdd(gen, 0u);
        const unsigned arrived = atomicAdd(cnt, 1u) + 1u;
        if (arrived == nblk) {
            atomicExch(cnt, 0u);            // reset before release
            __threadfence();
            atomicAdd(gen, 1u);             // release waiters
        } else {
            while (atomicAdd(gen, 0u) == gsnap)
                __builtin_amdgcn_s_sleep(2);
        }
    }
    __syncthreads();
    __threadfence();            // acquire: see others' stores
}

// ---------------------------------------------------------------------------
// prep (merged): blocks 0..15 build Wxt (xw^T bf16, 48->64 pad);
// blocks 16..143 transpose glu_w -> Wt (512x256 bf16)
// ---------------------------------------------------------------------------
__global__ __launch_bounds__(256) void k_prep(
    const float* __restrict__ xw, const float* __restrict__ gw,
    unsigned short* __restrict__ Wxt, unsigned short* __restrict__ Wt)
{
    __shared__ unsigned short s[32][33];
    const int bid = blockIdx.x;
    const int t = threadIdx.x;
    if (bid < 16) {
        const int idx = bid * 256 + t;
        const int n  = idx >> 6;
        const int k0 = (idx & 63) * 4;
        #pragma unroll
        for (int i = 0; i < 4; ++i) {
            float v = (n < 48) ? xw[(size_t)(k0 + i) * 48 + n] : 0.f;
            Wxt[(size_t)n * DD + k0 + i] = f2bf(v);
        }
    } else {
        const int bb = bid - 16;
        const int bx = bb & 15, by = bb >> 4;
        const int r = t >> 5, cc = t & 31;
        #pragma unroll
        for (int i = 0; i < 4; ++i)
            s[r + 8*i][cc] = f2bf(gw[(size_t)(by*32 + r + 8*i)*512 + bx*32 + cc]);
        __syncthreads();
        #pragma unroll
        for (int i = 0; i < 4; ++i)
            Wt[(size_t)(bx*32 + r + 8*i)*256 + by*32 + cc] = s[cc][r + 8*i];
    }
}

// ===========================================================================
// PRIMARY: single fused kernel, 512 blocks (chunk = 64 rows), hand barrier.
// __launch_bounds__(256,2): VGPR<=256 -> 2 blocks/CU by regs; LDS 49.5KB ->
// 3 blocks/CU; need exactly 2 -> all 512 co-resident, barrier safe.
// LN -> x_proj MFMA -> dt+scan1 -> BAR -> combine(blk<256) -> BAR -> scan2+gelu
// ===========================================================================
template<bool FAST>
__device__ __forceinline__ void fused_scan1(
    const float (*sdt)[20], const unsigned short (*As)[264],
    const float (*sB)[17], const float* wj, float bia,
    const float* al, int t, float* h, float* dsum)
{
    #pragma unroll 2
    for (int l = 0; l < LCF; ++l) {
        float acc = bia;
        #pragma unroll
        for (int j = 0; j < 16; ++j)
            acc = fmaf(sdt[l][j], wj[j], acc);
        const float sp = (acc > 15.f) ? acc
            : 0.69314718f * log2f(1.f + exp2f(acc * 1.44269504f));
        const float dl = bf2f(f2bf(sp));
        const float xl = bf2f(As[l][t]);
        const float dx = dl * xl;
        *dsum += dl;
        float e[NN];
        if (FAST) pow_tree(exp2f(al[0]*dl), e);
        else {
            #pragma unroll
            for (int n = 0; n < NN; ++n) e[n] = exp2f(al[n]*dl);
        }
        #pragma unroll
        for (int n = 0; n < NN; ++n)
            h[n] = fmaf(e[n], h[n], dx * sB[l][n]);
    }
}

template<bool FAST>
__device__ __forceinline__ void fused_scan2(
    const float (*sdt)[20], const unsigned short (*As)[264],
    const float (*sB)[17], const float (*sC)[17],
    const float* wj, float bia, const float* al, int t,
    float* h, float dsk, size_t m0, unsigned short* __restrict__ g)
{
    #pragma unroll 2
    for (int l = 0; l < LCF; ++l) {
        float acc = bia;
        #pragma unroll
        for (int j = 0; j < 16; ++j)
            acc = fmaf(sdt[l][j], wj[j], acc);
        const float sp = (acc > 15.f) ? acc
            : 0.69314718f * log2f(1.f + exp2f(acc * 1.44269504f));
        const float dl = bf2f(f2bf(sp));
        const float xl = bf2f(As[l][t]);
        const float dx = dl * xl;
        float e[NN];
        if (FAST) pow_tree(exp2f(al[0]*dl), e);
        else {
            #pragma unroll
            for (int n = 0; n < NN; ++n) e[n] = exp2f(al[n]*dl);
        }
        float yb[4] = {0.f, 0.f, 0.f, 0.f};
        #pragma unroll
        for (int n = 0; n < NN; ++n) {
            h[n] = fmaf(e[n], h[n], dx * sB[l][n]);
            yb[n & 3] = fmaf(h[n], sC[l][n], yb[n & 3]);
        }
        const float vv = (yb[0]+yb[1]) + (yb[2]+yb[3]) + xl * dsk;
        const float u  = 0.7978845608f * (vv + 0.044715f*vv*vv*vv);
        const float t2 = exp2f(2.8853900818f * u);
        const float th = 1.f - 2.f/(t2 + 1.f);
        g[(m0 + l)*DD + t] = f2bf(0.5f * vv * (1.f + th));
    }
}

__global__ __launch_bounds__(256, 2) void k_fused(
    const float* __restrict__ x,
    const float* __restrict__ ln_w,
    const float* __restrict__ ln_b,
    const unsigned short* __restrict__ Wxt,
    const float* __restrict__ dtw,
    const float* __restrict__ dtb,
    const float* __restrict__ A_log,
    const float* __restrict__ Dskip,
    float* __restrict__ S,
    float* __restrict__ Dsum,
    float* __restrict__ Hin,
    unsigned short* __restrict__ g,
    unsigned* __restrict__ bar)
{
    const int t = threadIdx.x;
    const int blk = blockIdx.x;            // b*CHF + c
    const size_t m0 = (size_t)blk * LCF;   // 64-row chunk base

    __shared__ unsigned short As[LCF][264];          // 33 KB, persists
    __shared__ float sdt[LCF][20];                   // persists (phase 3 reuse)
    __shared__ float sB[LCF][17];
    __shared__ float sC[LCF][17];
    __shared__ float slnw[256], slnb[256], sdtb[256];

    // ---- stage small vectors
    {
        const int tt = t & 63;
        if (t < 64)       *(float4*)&slnw[tt*4] = *(const float4*)&ln_w[tt*4];
        else if (t < 128) *(float4*)&slnb[tt*4] = *(const float4*)&ln_b[tt*4];
        else if (t < 192) *(float4*)&sdtb[tt*4] = *(const float4*)&dtb[tt*4];
    }

    // ---- per-thread (column t) constants
    float wj[16];
    #pragma unroll
    for (int j = 0; j < 16; ++j) wj[j] = dtw[j*DD + t];
    float al[NN];
    bool fast = true;
    #pragma unroll
    for (int n = 0; n < NN; ++n) {
        al[n] = -expf(A_log[t*NN + n]) * 1.44269504f;
        fast = fast && (fabsf(al[n] - (n+1)*al[0]) <= 1e-3f*fabsf(al[n]) + 1e-6f);
    }
    const float dsk = Dskip[t];
    __syncthreads();   // small-vector staging complete

    // ---- LN: two 32-row halves (8 threads/row, strided columns)
    const int seg = t & 7;
    for (int half = 0; half < 2; ++half) {
        const int row = (t >> 3) + 32*half;
        const size_t grow = m0 + row;
        float v[32];
        #pragma unroll
        for (int i = 0; i < 8; ++i)
            *(float4*)&v[i*4] = *(const float4*)(x + grow*DD + i*32 + seg*4);
        float s = 0.f, q = 0.f;
        #pragma unroll
        for (int i = 0; i < 32; ++i) { s += v[i]; q = fmaf(v[i], v[i], q); }
        #pragma unroll
        for (int o = 1; o < 8; o <<= 1) {
            s += __shfl_xor(s, o);
            q += __shfl_xor(q, o);
        }
        const float mu = s * (1.f/DD);
        const float rs = rsqrtf(q * (1.f/DD) - mu*mu + 1e-5f);
        #pragma unroll
        for (int i = 0; i < 8; ++i) {
            const int c = i*32 + seg*4;
            const float4 wv = *(const float4*)&slnw[c];
            const float4 bv = *(const float4*)&slnb[c];
            unsigned short o16[4];
            o16[0] = f2bf((v[i*4+0]-mu)*rs*wv.x + bv.x);
            o16[1] = f2bf((v[i*4+1]-mu)*rs*wv.y + bv.y);
            o16[2] = f2bf((v[i*4+2]-mu)*rs*wv.z + bv.z);
            o16[3] = f2bf((v[i*4+3]-mu)*rs*wv.w + bv.w);
            *(bf16x4*)&As[row][c] = *(bf16x4*)&o16[0];
        }
    }
    __syncthreads();

    // ---- x_proj MFMA: (64x256)@(256x48). Wave w owns rows w*16..w*16+16,
    // computes 3 col-fragments (dt | B | C). B-frags direct from global Wxt.
    {
        const int w = t >> 6, lane = t & 63;
        const int cl = lane & 15, rq = lane >> 4;
        const int mrow = w * 16;
        f32x4 aDt = {0.f,0.f,0.f,0.f}, aB = {0.f,0.f,0.f,0.f}, aC = {0.f,0.f,0.f,0.f};
        #pragma unroll
        for (int k0 = 0; k0 < 256; k0 += 32) {
            const bf16x8 a  = *(const bf16x8*)&As[mrow + cl][k0 + rq*8];
            const bf16x8 b0 = *(const bf16x8*)&Wxt[(size_t)(cl)*DD      + k0 + rq*8];
            const bf16x8 b1 = *(const bf16x8*)&Wxt[(size_t)(16+cl)*DD   + k0 + rq*8];
            const bf16x8 b2 = *(const bf16x8*)&Wxt[(size_t)(32+cl)*DD   + k0 + rq*8];
            aDt = __builtin_amdgcn_mfma_f32_16x16x32_bf16(a, b0, aDt, 0, 0, 0);
            aB  = __builtin_amdgcn_mfma_f32_16x16x32_bf16(a, b1, aB,  0, 0, 0);
            aC  = __builtin_amdgcn_mfma_f32_16x16x32_bf16(a, b2, aC,  0, 0, 0);
        }
        #pragma unroll
        for (int r = 0; r < 4; ++r) {
            const int rr = mrow + rq*4 + r;
            sdt[rr][cl] = aDt[r];
            sB[rr][cl]  = aB[r];
            sC[rr][cl]  = aC[r];
        }
    }
    __syncthreads();

    // ---- phase 1: dt_proj + softplus + scan1 (thread t = column d)
    float h[NN];
    #pragma unroll
    for (int n = 0; n < NN; ++n) h[n] = 0.f;
    float dsum = 0.f;
    const float bia = sdtb[t];
    if (fast) fused_scan1<true >(sdt, As, sB, wj, bia, al, t, h, &dsum);
    else      fused_scan1<false>(sdt, As, sB, wj, bia, al, t, h, &dsum);
    {
        const size_t o = (size_t)blk * NN * DD + t;
        #pragma unroll
        for (int n = 0; n < NN; ++n) S[o + n*DD] = h[n];
        Dsum[(size_t)blk*DD + t] = dsum;
    }
    gridBarrier(bar, BB*CHF);

    // ---- phase 2: combine (blocks 0..255 = one (b,n) pair), 8-deep batches
    if (blk < 256) {
        const int n2 = blk & 15, b2 = blk >> 4;
        const float al2 = -expf(A_log[t*NN + n2]) * 1.44269504f;
        float hh = 0.f;
        for (int c0 = 0; c0 < CHF; c0 += 8) {
            float ds8[8], s8[8];
            #pragma unroll
            for (int i = 0; i < 8; ++i) {
                const size_t bc = (size_t)b2*CHF + c0 + i;
                ds8[i] = Dsum[bc*DD + t];
                s8[i]  = S[(bc*NN + n2)*DD + t];
            }
            #pragma unroll
            for (int i = 0; i < 8; ++i) {
                const size_t bc = (size_t)b2*CHF + c0 + i;
                Hin[(bc*NN + n2)*DD + t] = hh;
                hh = fmaf(exp2f(al2 * ds8[i]), hh, s8[i]);
            }
        }
    }
    gridBarrier(bar, BB*CHF);

    // ---- phase 3: scan2 + gelu -> g (delta recomputed from sdt, bit-identical)
    {
        const size_t ob = (size_t)blk * NN * DD + t;
        #pragma unroll
        for (int n = 0; n < NN; ++n) h[n] = Hin[ob + n*DD];
    }
    if (fast) fused_scan2<true >(sdt, As, sB, sC, wj, bia, al, t, h, dsk, m0, g);
    else      fused_scan2<false>(sdt, As, sB, sC, wj, bia, al, t, h, dsk, m0, g);
}

// ===========================================================================
// FALLBACK (proven 110us): k_ln_scan1 + k_combine + k_scan2
// ===========================================================================
template<bool FAST>
__device__ __forceinline__ void dt_scan1_fb(
    const float (*sdt)[20], const unsigned short (*As)[264],
    const float (*sB)[16], const float* wj, float bia,
    const float* al, int d, size_t m0,
    unsigned short* __restrict__ delta,
    float* h, float* dsum)
{
    #pragma unroll 4
    for (int l = 0; l < LCB; ++l) {
        float acc = bia;
        #pragma unroll
        for (int j = 0; j < 16; ++j)
            acc = fmaf(sdt[l][j], wj[j], acc);
        const float sp = (acc > 15.f) ? acc
            : 0.69314718f * log2f(1.f + exp2f(acc * 1.44269504f));
        const unsigned short dbits = f2bf(sp);
        delta[(m0 + l)*DD + d] = dbits;
        const float dl = bf2f(dbits);
        const float xl = bf2f(As[l][d]);
        const float dx = dl * xl;
        *dsum += dl;
        float e[NN];
        if (FAST) pow_tree(exp2f(al[0]*dl), e);
        else {
            #pragma unroll
            for (int n = 0; n < NN; ++n) e[n] = exp2f(al[n]*dl);
        }
        #pragma unroll
        for (int n = 0; n < NN; ++n)
            h[n] = fmaf(e[n], h[n], dx * sB[l][n]);
    }
}

__global__ __launch_bounds__(256) void k_ln_scan1(
    const float* __restrict__ x,
    const float* __restrict__ ln_w,
    const float* __restrict__ ln_b,
    const unsigned short* __restrict__ Wxt,
    const float* __restrict__ dtw,
    const float* __restrict__ dtb,
    const float* __restrict__ A_log,
    unsigned short* __restrict__ xln,
    unsigned short* __restrict__ delta,
    float* __restrict__ Bv,
    float* __restrict__ Cv,
    float* __restrict__ S,
    float* __restrict__ Dsum)
{
    const int t = threadIdx.x;
    const int blk = blockIdx.x;
    const size_t m0 = (size_t)blk * 32;
    const int row = t >> 3, seg = t & 7;
    const size_t grow = m0 + row;

    __shared__ unsigned short As[32][264];
    __shared__ float sdt[32][20];
    __shared__ float sB[32][16];
    __shared__ float slnw[256], slnb[256], sdtb[256];

    {
        const int tt = t & 63;
        if (t < 64)       *(float4*)&slnw[tt*4] = *(const float4*)&ln_w[tt*4];
        else if (t < 128) *(float4*)&slnb[tt*4] = *(const float4*)&ln_b[tt*4];
        else if (t < 192) *(float4*)&sdtb[tt*4] = *(const float4*)&dtb[tt*4];
    }
    float wj[16];
    #pragma unroll
    for (int j = 0; j < 16; ++j) wj[j] = dtw[j*DD + t];
    float al[NN];
    bool fast = true;
    #pragma unroll
    for (int n = 0; n < NN; ++n) {
        al[n] = -expf(A_log[t*NN + n]) * 1.44269504f;
        fast = fast && (fabsf(al[n] - (n+1)*al[0]) <= 1e-3f*fabsf(al[n]) + 1e-6f);
    }
    float v[32];
    #pragma unroll
    for (int i = 0; i < 8; ++i)
        *(float4*)&v[i*4] = *(const float4*)(x + grow*DD + i*32 + seg*4);
    float s = 0.f, q = 0.f;
    #pragma unroll
    for (int i = 0; i < 32; ++i) { s += v[i]; q = fmaf(v[i], v[i], q); }
    #pragma unroll
    for (int o = 1; o < 8; o <<= 1) {
        s += __shfl_xor(s, o);
        q += __shfl_xor(q, o);
    }
    const float mu = s * (1.f/DD);
    const float rs = rsqrtf(q * (1.f/DD) - mu*mu + 1e-5f);
    __syncthreads();
    #pragma unroll
    for (int i = 0; i < 8; ++i) {
        const int c = i*32 + seg*4;
        const float4 wv = *(const float4*)&slnw[c];
        const float4 bv = *(const float4*)&slnb[c];
        unsigned short o16[4];
        o16[0] = f2bf((v[i*4+0]-mu)*rs*wv.x + bv.x);
        o16[1] = f2bf((v[i*4+1]-mu)*rs*wv.y + bv.y);
        o16[2] = f2bf((v[i*4+2]-mu)*rs*wv.z + bv.z);
        o16[3] = f2bf((v[i*4+3]-mu)*rs*wv.w + bv.w);
        *(bf16x4*)&xln[grow*DD + c] = *(bf16x4*)&o16[0];
        *(bf16x4*)&As[row][c]       = *(bf16x4*)&o16[0];
    }
    __syncthreads();
    {
        const int w = t >> 6, lane = t & 63;
        const int cl = lane & 15, rq = lane >> 4;
        const int mh = (w & 1) * 16;
        const int nh = (w >> 1) * 32;
        f32x4 acc0 = {0.f,0.f,0.f,0.f}, acc1 = {0.f,0.f,0.f,0.f};
        #pragma unroll
        for (int k0 = 0; k0 < 256; k0 += 32) {
            const bf16x8 a  = *(const bf16x8*)&As[mh + cl][k0 + rq*8];
            const bf16x8 b0 = *(const bf16x8*)&Wxt[(size_t)(nh + cl)*DD + k0 + rq*8];
            acc0 = __builtin_amdgcn_mfma_f32_16x16x32_bf16(a, b0, acc0, 0, 0, 0);
            if (w < 2) {
                const bf16x8 b1 = *(const bf16x8*)&Wxt[(size_t)(nh + 16 + cl)*DD + k0 + rq*8];
                acc1 = __builtin_amdgcn_mfma_f32_16x16x32_bf16(a, b1, acc1, 0, 0, 0);
            }
        }
        if (w < 2) {
            #pragma unroll
            for (int r = 0; r < 4; ++r) {
                const int rr = mh + rq*4 + r;
                sdt[rr][cl] = acc0[r];
                sB[rr][cl]  = acc1[r];
                Bv[(m0 + rr)*NN + cl] = acc1[r];
            }
        } else {
            #pragma unroll
            for (int r = 0; r < 4; ++r)
                Cv[(m0 + mh + rq*4 + r)*NN + cl] = acc0[r];
        }
    }
    __syncthreads();
    float h[NN];
    #pragma unroll
    for (int n = 0; n < NN; ++n) h[n] = 0.f;
    float dsum = 0.f;
    const float bia = sdtb[t];
    if (fast) dt_scan1_fb<true >(sdt, As, sB, wj, bia, al, t, m0, delta, h, &dsum);
    else      dt_scan1_fb<false>(sdt, As, sB, wj, bia, al, t, m0, delta, h, &dsum);
    const size_t o = (size_t)blk * NN * DD + t;
    #pragma unroll
    for (int n = 0; n < NN; ++n) S[o + n*DD] = h[n];
    Dsum[(size_t)blk*DD + t] = dsum;
}

__global__ __launch_bounds__(256) void k_combine(
    const float* __restrict__ S, const float* __restrict__ Dsum,
    const float* __restrict__ A_log, float* __restrict__ Hin)
{
    const int bi = blockIdx.x;
    const int d = threadIdx.x;
    const int n = bi & 15;
    const int b = bi >> 4;
    const float al = -expf(A_log[d*NN + n]) * 1.44269504f;
    float h = 0.f;
    for (int c0 = 0; c0 < CHB; c0 += 8) {
        float ds8[8], s8[8];
        #pragma unroll
        for (int i = 0; i < 8; ++i) {
            const size_t blk = (size_t)b*CHB + c0 + i;
            ds8[i] = Dsum[blk*DD + d];
            s8[i]  = S[(blk*NN + n)*DD + d];
        }
        #pragma unroll
        for (int i = 0; i < 8; ++i) {
            const size_t blk = (size_t)b*CHB + c0 + i;
            Hin[(blk*NN + n)*DD + d] = h;
            h = fmaf(exp2f(al * ds8[i]), h, s8[i]);
        }
    }
}

template<bool FAST>
__device__ __forceinline__ void scan2_impl_fb(
    const unsigned short (*sD)[264], const unsigned short (*sX)[264],
    const float (*sB)[16], const float (*sC)[16],
    const float* al, int d, float* h, float dsk,
    size_t gout, unsigned short* __restrict__ g)
{
    #pragma unroll 4
    for (int l = 0; l < LCB; ++l) {
        const float dl = bf2f(sD[l][d]);
        const float xl = bf2f(sX[l][d]);
        const float dx = dl * xl;
        float e[NN];
        if (FAST) pow_tree(exp2f(al[0]*dl), e);
        else {
            #pragma unroll
            for (int n = 0; n < NN; ++n) e[n] = exp2f(al[n]*dl);
        }
        float yb[4] = {0.f, 0.f, 0.f, 0.f};
        #pragma unroll
        for (int n = 0; n < NN; ++n) {
            h[n] = fmaf(e[n], h[n], dx * sB[l][n]);
            yb[n & 3] = fmaf(h[n], sC[l][n], yb[n & 3]);
        }
        const float vv = (yb[0]+yb[1]) + (yb[2]+yb[3]) + xl * dsk;
        const float u  = 0.7978845608f * (vv + 0.044715f*vv*vv*vv);
        const float t2 = exp2f(2.8853900818f * u);
        const float th = 1.f - 2.f/(t2 + 1.f);
        g[gout + (size_t)l*DD] = f2bf(0.5f * vv * (1.f + th));
    }
}

__global__ __launch_bounds__(256) void k_scan2(
    const unsigned short* __restrict__ delta,
    const unsigned short* __restrict__ xln,
    const float* __restrict__ Bv,
    const float* __restrict__ Cv,
    const float* __restrict__ A_log,
    const float* __restrict__ Hin,
    const float* __restrict__ Dskip,
    unsigned short* __restrict__ g)
{
    const int blk = blockIdx.x;
    const int c = blk & (CHB-1);
    const int b = blk >> 6;
    const int d = threadIdx.x;
    const int l0 = c * LCB;
    __shared__ unsigned short sD[LCB][264];
    __shared__ unsigned short sX[LCB][264];
    __shared__ float sB[LCB][16], sC[LCB][16];
    {
        const int sr = d >> 3, sc = (d & 7) * 32;
        const size_t gbase = ((size_t)b*LL + l0 + sr)*DD + sc;
        #pragma unroll
        for (int i = 0; i < 4; ++i) {
            *(bf16x8*)&sD[sr][sc + i*8] = *(const bf16x8*)&delta[gbase + i*8];
            *(bf16x8*)&sX[sr][sc + i*8] = *(const bf16x8*)&xln  [gbase + i*8];
        }
        if (d < 128) {
            const int l = d >> 2, qq = (d & 3) * 4;
            *(float4*)&sB[l][qq] = *(const float4*)&Bv[((size_t)b*LL + l0 + l)*NN + qq];
        } else {
            const int dd = d - 128;
            const int l = dd >> 2, qq = (dd & 3) * 4;
            *(float4*)&sC[l][qq] = *(const float4*)&Cv[((size_t)b*LL + l0 + l)*NN + qq];
        }
    }
    float al[NN];
    bool fast = true;
    #pragma unroll
    for (int n = 0; n < NN; ++n) {
        al[n] = -expf(A_log[d*NN + n]) * 1.44269504f;
        fast = fast && (fabsf(al[n] - (n+1)*al[0]) <= 1e-3f*fabsf(al[n]) + 1e-6f);
    }
    float h[NN];
    const size_t ob = (size_t)blk * NN * DD + d;
    #pragma unroll
    for (int n = 0; n < NN; ++n) h[n] = Hin[ob + n*DD];
    const float dsk = Dskip[d];
    __syncthreads();
    const size_t gout = ((size_t)b*LL + l0)*DD + d;
    if (fast) scan2_impl_fb<true >(sD, sX, sB, sC, al, d, h, dsk, gout, g);
    else      scan2_impl_fb<false>(sD, sX, sB, sC, al, d, h, dsk, gout, g);
}

// ---------------------------------------------------------------------------
// GLU GEMM (32768x256 @ 256x512) + bias + sigmoid gate + skip
// ---------------------------------------------------------------------------
__global__ __launch_bounds__(256) void k_glu(
    const unsigned short* __restrict__ g,
    const unsigned short* __restrict__ Wt,
    const float* __restrict__ gb,
    const float* __restrict__ x,
    float* __restrict__ out)
{
    __shared__ unsigned short As[64][40];
    __shared__ unsigned short Bl[64][40];
    __shared__ unsigned short Bh[64][40];
    const int n0 = blockIdx.x * 64;
    const int m0 = blockIdx.y * 64;
    const int t = threadIdx.x;
    const int w = t >> 6, lane = t & 63;
    const int r = t >> 2, q = t & 3;
    const int cl = lane & 15, rq = lane >> 4;
    f32x4 accL[4], accH[4];
    const f32x4 zz = {0.f, 0.f, 0.f, 0.f};
    #pragma unroll
    for (int nf = 0; nf < 4; ++nf) { accL[nf] = zz; accH[nf] = zz; }

    for (int k0 = 0; k0 < 256; k0 += 32) {
        *(bf16x8*)(&As[r][q*8]) = *(const bf16x8*)(&g [(size_t)(m0+r)*DD + k0 + q*8]);
        *(bf16x8*)(&Bl[r][q*8]) = *(const bf16x8*)(&Wt[(size_t)(n0+r)*DD + k0 + q*8]);
        *(bf16x8*)(&Bh[r][q*8]) = *(const bf16x8*)(&Wt[(size_t)(n0+256+r)*DD + k0 + q*8]);
        __syncthreads();
        const bf16x8 a = *(const bf16x8*)(&As[w*16 + cl][rq*8]);
        #pragma unroll
        for (int nf = 0; nf < 4; ++nf) {
            const bf16x8 bl = *(const bf16x8*)(&Bl[nf*16 + cl][rq*8]);
            const bf16x8 bh = *(const bf16x8*)(&Bh[nf*16 + cl][rq*8]);
            accL[nf] = __builtin_amdgcn_mfma_f32_16x16x32_bf16(a, bl, accL[nf], 0, 0, 0);
            accH[nf] = __builtin_amdgcn_mfma_f32_16x16x32_bf16(a, bh, accH[nf], 0, 0, 0);
        }
        __syncthreads();
    }
    #pragma unroll
    for (int nf = 0; nf < 4; ++nf) {
        const int j = n0 + nf*16 + cl;
        const float bL = gb[j];
        const float bH = gb[j + 256];
        #pragma unroll
        for (int rr = 0; rr < 4; ++rr) {
            const int m = m0 + w*16 + rq*4 + rr;
            const float lo = accL[nf][rr] + bL;
            const float hi = accH[nf][rr] + bH;
            const float sg = 1.f / (1.f + exp2f(-1.44269504f * hi));
            out[(size_t)m*DD + j] = lo * sg + x[(size_t)m*DD + j];
        }
    }
}

extern "C" void kernel_launch(void* const* d_in, const int* in_sizes, int n_in,
                              void* d_out, int out_size, void* d_ws, size_t ws_size,
                              hipStream_t stream)
{
    const float* x    = (const float*)d_in[0];
    const float* ln_w = (const float*)d_in[1];
    const float* ln_b = (const float*)d_in[2];
    const float* xpw  = (const float*)d_in[3];
    const float* dtw  = (const float*)d_in[4];
    const float* dtb  = (const float*)d_in[5];
    const float* alog = (const float*)d_in[6];
    const float* dsk  = (const float*)d_in[7];
    const float* gw   = (const float*)d_in[8];
    const float* gb   = (const float*)d_in[9];
    float* out = (float*)d_out;

    char* ws = (char*)d_ws;
    size_t off = 0;
    auto alloc = [&](size_t bytes) {
        char* p = ws + off; off += (bytes + 255) & ~(size_t)255; return p;
    };
    unsigned*       bar    = (unsigned*)      alloc(256);
    unsigned short* xln    = (unsigned short*)alloc((size_t)BB*LL*DD*2);
    unsigned short* deltaG = (unsigned short*)alloc((size_t)BB*LL*DD*2);
    float*          Bvp    = (float*)         alloc((size_t)BB*LL*NN*4);
    float*          Cvp    = (float*)         alloc((size_t)BB*LL*NN*4);
    float*          S      = (float*)         alloc((size_t)BB*CHB*NN*DD*4);
    float*          Dsum   = (float*)         alloc((size_t)BB*CHB*DD*4);
    float*          Hin    = (float*)         alloc((size_t)BB*CHB*NN*DD*4);
    unsigned short* Wt     = (unsigned short*)alloc((size_t)512*256*2);
    unsigned short* Wxt    = (unsigned short*)alloc((size_t)64*256*2);
    unsigned short* g      = deltaG;   // g shares the delta buffer in both paths

    k_prep<<<144, 256, 0, stream>>>(xpw, gw, Wxt, Wt);

    // PHYSICAL capacity gate. __launch_bounds__(256,2) caps k_fused at 256
    // VGPR (regCap=2); LDS 49.5KB -> 3 blocks/CU on gfx950's 160KB; need 2.
    bool coop = false;
    {
        int dev = 0;
        hipDeviceProp_t prop;
        hipFuncAttributes fa;
        if (hipGetDevice(&dev) == hipSuccess &&
            hipGetDeviceProperties(&prop, dev) == hipSuccess &&
            hipFuncGetAttributes(&fa, (const void*)k_fused) == hipSuccess) {
            const bool gfx950 = strstr(prop.gcnArchName, "gfx950") != nullptr;
            const size_t ldsPerCU = gfx950 ? (size_t)163840
                                           : (size_t)prop.maxSharedMemoryPerMultiProcessor;
            const size_t ldsBlk = fa.sharedSizeBytes ? fa.sharedSizeBytes : 1;
            long ldsCap = (long)(ldsPerCU / ldsBlk);
            long regCap = fa.numRegs > 0 ? (512 / fa.numRegs) : 8;  // waves/SIMD = blocks/CU for 4-wave blocks
            long thrCap = prop.maxThreadsPerMultiProcessor / 256;
            long cap = ldsCap;
            if (regCap < cap) cap = regCap;
            if (thrCap < cap) cap = thrCap;
            coop = (cap * (long)prop.multiProcessorCount >= (long)(BB*CHF));
        }
    }

    if (coop) {
        hipMemsetAsync(bar, 0, 256, stream);
        k_fused<<<BB*CHF, 256, 0, stream>>>(x, ln_w, ln_b, Wxt, dtw, dtb, alog,
                                            dsk, S, Dsum, Hin, g, bar);
    } else {
        k_ln_scan1<<<BB*CHB, 256, 0, stream>>>(x, ln_w, ln_b, Wxt, dtw, dtb, alog,
                                               xln, deltaG, Bvp, Cvp, S, Dsum);
        k_combine<<<256, 256, 0, stream>>>(S, Dsum, alog, Hin);
        k_scan2<<<BB*CHB, 256, 0, stream>>>(deltaG, xln, Bvp, Cvp, alog, Hin, dsk, g);
    }

    k_glu<<<dim3(4, 512), 256, 0, stream>>>(g, Wt, gb, x, out);
}

// Round 13
// 118.447 us; speedup vs baseline: 2.2114x; 2.2114x over previous
//
#include <hip/hip_runtime.h>
#include <hip/hip_bf16.h>
#include <cstring>

#define BB 16
#define LL 2048
#define DD 256
#define NN 16
#define RR 16
// primary: 128 chunks of 16 rows (2048 blocks). fallback: 64 chunks of 32 rows.
#define CH2 128
#define LC2 16
#define CHB 64
#define LCB 32

static __device__ __forceinline__ float bf2f(unsigned short u) {
    return __uint_as_float(((unsigned)u) << 16);
}
static __device__ __forceinline__ unsigned short f2bf(float f) {
    unsigned u = __float_as_uint(f);
    u += 0x7FFFu + ((u >> 16) & 1u);
    return (unsigned short)(u >> 16);
}

typedef __attribute__((ext_vector_type(8))) short bf16x8;
typedef __attribute__((ext_vector_type(4))) short bf16x4;
typedef __attribute__((ext_vector_type(4))) float f32x4;

// e[n] = E^(n+1), depth-4 product tree
static __device__ __forceinline__ void pow_tree(float E, float* e) {
    e[0] = E;
    e[1] = E * E;
    e[2] = e[1] * E;
    e[3] = e[1] * e[1];
    e[4] = e[3] * e[0];  e[5] = e[3] * e[1];  e[6] = e[3] * e[2];  e[7] = e[3] * e[3];
    e[8] = e[7] * e[0];  e[9] = e[7] * e[1];  e[10] = e[7] * e[2]; e[11] = e[7] * e[3];
    e[12] = e[7] * e[4]; e[13] = e[7] * e[5]; e[14] = e[7] * e[6]; e[15] = e[7] * e[7];
}

// ---------------------------------------------------------------------------
// prep (merged): blocks 0..15 build Wxt (xw^T bf16, 48->64 pad);
// blocks 16..143 transpose glu_w -> Wt (512x256 bf16)
// ---------------------------------------------------------------------------
__global__ __launch_bounds__(256) void k_prep(
    const float* __restrict__ xw, const float* __restrict__ gw,
    unsigned short* __restrict__ Wxt, unsigned short* __restrict__ Wt)
{
    __shared__ unsigned short s[32][33];
    const int bid = blockIdx.x;
    const int t = threadIdx.x;
    if (bid < 16) {
        const int idx = bid * 256 + t;
        const int n  = idx >> 6;
        const int k0 = (idx & 63) * 4;
        #pragma unroll
        for (int i = 0; i < 4; ++i) {
            float v = (n < 48) ? xw[(size_t)(k0 + i) * 48 + n] : 0.f;
            Wxt[(size_t)n * DD + k0 + i] = f2bf(v);
        }
    } else {
        const int bb = bid - 16;
        const int bx = bb & 15, by = bb >> 4;
        const int r = t >> 5, cc = t & 31;
        #pragma unroll
        for (int i = 0; i < 4; ++i)
            s[r + 8*i][cc] = f2bf(gw[(size_t)(by*32 + r + 8*i)*512 + bx*32 + cc]);
        __syncthreads();
        #pragma unroll
        for (int i = 0; i < 4; ++i)
            Wt[(size_t)(bx*32 + r + 8*i)*256 + by*32 + cc] = s[cc][r + 8*i];
    }
}

// ===========================================================================
// PRIMARY path: 16-row chunks, 2048 blocks -> ~24 waves/CU (vs 16 at 32-row)
// ===========================================================================

// ---- LN + x_proj MFMA + column dt_proj (4-banked) + softplus + scan1 ----
template<bool FAST>
__device__ __forceinline__ void dt_scan1_16(
    const float (*sdt)[20], const unsigned short (*As)[264],
    const float (*sB)[17], const float* wj, float bia,
    const float* al, int d, size_t m0,
    unsigned short* __restrict__ delta,
    float* h, float* dsum)
{
    #pragma unroll 4
    for (int l = 0; l < LC2; ++l) {
        float ab0 = bia, ab1 = 0.f, ab2 = 0.f, ab3 = 0.f;
        #pragma unroll
        for (int j = 0; j < 16; j += 4) {
            ab0 = fmaf(sdt[l][j+0], wj[j+0], ab0);
            ab1 = fmaf(sdt[l][j+1], wj[j+1], ab1);
            ab2 = fmaf(sdt[l][j+2], wj[j+2], ab2);
            ab3 = fmaf(sdt[l][j+3], wj[j+3], ab3);
        }
        const float acc = (ab0 + ab1) + (ab2 + ab3);
        const float sp = (acc > 15.f) ? acc
            : 0.69314718f * log2f(1.f + exp2f(acc * 1.44269504f));
        const unsigned short dbits = f2bf(sp);
        delta[(m0 + l)*DD + d] = dbits;
        const float dl = bf2f(dbits);
        const float xl = bf2f(As[l][d]);
        const float dx = dl * xl;
        *dsum += dl;
        float e[NN];
        if (FAST) pow_tree(exp2f(al[0]*dl), e);
        else {
            #pragma unroll
            for (int n = 0; n < NN; ++n) e[n] = exp2f(al[n]*dl);
        }
        #pragma unroll
        for (int n = 0; n < NN; ++n)
            h[n] = fmaf(e[n], h[n], dx * sB[l][n]);
    }
}

__global__ __launch_bounds__(256) void k_ln_scan1_16(
    const float* __restrict__ x,
    const float* __restrict__ ln_w,
    const float* __restrict__ ln_b,
    const unsigned short* __restrict__ Wxt,
    const float* __restrict__ dtw,
    const float* __restrict__ dtb,
    const float* __restrict__ A_log,
    unsigned short* __restrict__ xln,
    unsigned short* __restrict__ delta,
    float* __restrict__ Bv,
    float* __restrict__ Cv,
    float* __restrict__ S,
    float* __restrict__ Dsum)
{
    const int t = threadIdx.x;
    const int blk = blockIdx.x;           // b*CH2 + c
    const size_t m0 = (size_t)blk * LC2;  // 16-row chunk base
    const int row = t >> 4, seg = t & 15;
    const size_t grow = m0 + row;

    __shared__ unsigned short As[LC2][264];
    __shared__ float sdt[LC2][20];
    __shared__ float sB[LC2][17];
    __shared__ float slnw[256], slnb[256], sdtb[256];

    {
        const int tt = t & 63;
        if (t < 64)       *(float4*)&slnw[tt*4] = *(const float4*)&ln_w[tt*4];
        else if (t < 128) *(float4*)&slnb[tt*4] = *(const float4*)&ln_b[tt*4];
        else if (t < 192) *(float4*)&sdtb[tt*4] = *(const float4*)&dtb[tt*4];
    }
    float wj[16];
    #pragma unroll
    for (int j = 0; j < 16; ++j) wj[j] = dtw[j*DD + t];
    float al[NN];
    bool fast = true;
    #pragma unroll
    for (int n = 0; n < NN; ++n) {
        al[n] = -expf(A_log[t*NN + n]) * 1.44269504f;
        fast = fast && (fabsf(al[n] - (n+1)*al[0]) <= 1e-3f*fabsf(al[n]) + 1e-6f);
    }

    // ---- LN: 16 threads/row, 16 floats/thread
    float v[16];
    #pragma unroll
    for (int i = 0; i < 4; ++i)
        *(float4*)&v[i*4] = *(const float4*)(x + grow*DD + i*64 + seg*4);
    float s = 0.f, q = 0.f;
    #pragma unroll
    for (int i = 0; i < 16; ++i) { s += v[i]; q = fmaf(v[i], v[i], q); }
    #pragma unroll
    for (int o = 1; o < 16; o <<= 1) {
        s += __shfl_xor(s, o);
        q += __shfl_xor(q, o);
    }
    const float mu = s * (1.f/DD);
    const float rs = rsqrtf(q * (1.f/DD) - mu*mu + 1e-5f);
    __syncthreads();
    #pragma unroll
    for (int i = 0; i < 4; ++i) {
        const int c = i*64 + seg*4;
        const float4 wv = *(const float4*)&slnw[c];
        const float4 bv = *(const float4*)&slnb[c];
        unsigned short o16[4];
        o16[0] = f2bf((v[i*4+0]-mu)*rs*wv.x + bv.x);
        o16[1] = f2bf((v[i*4+1]-mu)*rs*wv.y + bv.y);
        o16[2] = f2bf((v[i*4+2]-mu)*rs*wv.z + bv.z);
        o16[3] = f2bf((v[i*4+3]-mu)*rs*wv.w + bv.w);
        *(bf16x4*)&xln[grow*DD + c] = *(bf16x4*)&o16[0];
        *(bf16x4*)&As[row][c]       = *(bf16x4*)&o16[0];
    }
    __syncthreads();

    // ---- x_proj MFMA: (16x256)@(256x48); wave w<3 owns n-tile w (dt|B|C)
    {
        const int w = t >> 6, lane = t & 63;
        const int cl = lane & 15, rq = lane >> 4;
        if (w < 3) {
            f32x4 acc = {0.f,0.f,0.f,0.f};
            #pragma unroll
            for (int k0 = 0; k0 < 256; k0 += 32) {
                const bf16x8 a = *(const bf16x8*)&As[cl][k0 + rq*8];
                const bf16x8 b = *(const bf16x8*)&Wxt[(size_t)(w*16 + cl)*DD + k0 + rq*8];
                acc = __builtin_amdgcn_mfma_f32_16x16x32_bf16(a, b, acc, 0, 0, 0);
            }
            #pragma unroll
            for (int r = 0; r < 4; ++r) {
                const int rr = rq*4 + r;
                if (w == 0)      sdt[rr][cl] = acc[r];
                else if (w == 1) { sB[rr][cl] = acc[r]; Bv[(m0 + rr)*NN + cl] = acc[r]; }
                else             Cv[(m0 + rr)*NN + cl] = acc[r];
            }
        }
    }
    __syncthreads();

    // ---- dt_proj + softplus + scan1 (thread t = column d)
    float h[NN];
    #pragma unroll
    for (int n = 0; n < NN; ++n) h[n] = 0.f;
    float dsum = 0.f;
    const float bia = sdtb[t];
    if (fast) dt_scan1_16<true >(sdt, As, sB, wj, bia, al, t, m0, delta, h, &dsum);
    else      dt_scan1_16<false>(sdt, As, sB, wj, bia, al, t, m0, delta, h, &dsum);
    const size_t o = (size_t)blk * NN * DD + t;
    #pragma unroll
    for (int n = 0; n < NN; ++n) S[o + n*DD] = h[n];
    Dsum[(size_t)blk*DD + t] = dsum;
}

// ---- combine over 128 chunks ----
__global__ __launch_bounds__(256) void k_combine_128(
    const float* __restrict__ S, const float* __restrict__ Dsum,
    const float* __restrict__ A_log, float* __restrict__ Hin)
{
    const int bi = blockIdx.x;
    const int d = threadIdx.x;
    const int n = bi & 15;
    const int b = bi >> 4;
    const float al = -expf(A_log[d*NN + n]) * 1.44269504f;
    float h = 0.f;
    for (int c0 = 0; c0 < CH2; c0 += 8) {
        float ds8[8], s8[8];
        #pragma unroll
        for (int i = 0; i < 8; ++i) {
            const size_t blk = (size_t)b*CH2 + c0 + i;
            ds8[i] = Dsum[blk*DD + d];
            s8[i]  = S[(blk*NN + n)*DD + d];
        }
        #pragma unroll
        for (int i = 0; i < 8; ++i) {
            const size_t blk = (size_t)b*CH2 + c0 + i;
            Hin[(blk*NN + n)*DD + d] = h;
            h = fmaf(exp2f(al * ds8[i]), h, s8[i]);
        }
    }
}

// ---- scan2 over 16-row chunks ----
template<bool FAST>
__device__ __forceinline__ void scan2_16(
    const unsigned short (*sD)[264], const unsigned short (*sX)[264],
    const float (*sB)[16], const float (*sC)[16],
    const float* al, int d, float* h, float dsk,
    size_t gout, unsigned short* __restrict__ g)
{
    #pragma unroll 4
    for (int l = 0; l < LC2; ++l) {
        const float dl = bf2f(sD[l][d]);
        const float xl = bf2f(sX[l][d]);
        const float dx = dl * xl;
        float e[NN];
        if (FAST) pow_tree(exp2f(al[0]*dl), e);
        else {
            #pragma unroll
            for (int n = 0; n < NN; ++n) e[n] = exp2f(al[n]*dl);
        }
        float yb[4] = {0.f, 0.f, 0.f, 0.f};
        #pragma unroll
        for (int n = 0; n < NN; ++n) {
            h[n] = fmaf(e[n], h[n], dx * sB[l][n]);
            yb[n & 3] = fmaf(h[n], sC[l][n], yb[n & 3]);
        }
        const float vv = (yb[0]+yb[1]) + (yb[2]+yb[3]) + xl * dsk;
        const float u  = 0.7978845608f * (vv + 0.044715f*vv*vv*vv);
        const float t2 = exp2f(2.8853900818f * u);
        const float th = 1.f - 2.f/(t2 + 1.f);
        g[gout + (size_t)l*DD] = f2bf(0.5f * vv * (1.f + th));
    }
}

__global__ __launch_bounds__(256) void k_scan2_16(
    const unsigned short* __restrict__ delta,
    const unsigned short* __restrict__ xln,
    const float* __restrict__ Bv,
    const float* __restrict__ Cv,
    const float* __restrict__ A_log,
    const float* __restrict__ Hin,
    const float* __restrict__ Dskip,
    unsigned short* __restrict__ g)
{
    const int blk = blockIdx.x;
    const int c = blk & (CH2-1);
    const int b = blk >> 7;
    const int d = threadIdx.x;
    const int l0 = c * LC2;
    __shared__ unsigned short sD[LC2][264];
    __shared__ unsigned short sX[LC2][264];
    __shared__ float sB[LC2][16], sC[LC2][16];
    {
        const int sr = d >> 4, scc = (d & 15) * 16;
        const size_t gbase = ((size_t)b*LL + l0 + sr)*DD + scc;
        #pragma unroll
        for (int i = 0; i < 2; ++i) {
            *(bf16x8*)&sD[sr][scc + i*8] = *(const bf16x8*)&delta[gbase + i*8];
            *(bf16x8*)&sX[sr][scc + i*8] = *(const bf16x8*)&xln  [gbase + i*8];
        }
        if (d < 64) {
            const int l = d >> 2, qq = (d & 3) * 4;
            *(float4*)&sB[l][qq] = *(const float4*)&Bv[((size_t)b*LL + l0 + l)*NN + qq];
        } else if (d < 128) {
            const int dd = d - 64;
            const int l = dd >> 2, qq = (dd & 3) * 4;
            *(float4*)&sC[l][qq] = *(const float4*)&Cv[((size_t)b*LL + l0 + l)*NN + qq];
        }
    }
    float al[NN];
    bool fast = true;
    #pragma unroll
    for (int n = 0; n < NN; ++n) {
        al[n] = -expf(A_log[d*NN + n]) * 1.44269504f;
        fast = fast && (fabsf(al[n] - (n+1)*al[0]) <= 1e-3f*fabsf(al[n]) + 1e-6f);
    }
    float h[NN];
    const size_t ob = (size_t)blk * NN * DD + d;
    #pragma unroll
    for (int n = 0; n < NN; ++n) h[n] = Hin[ob + n*DD];
    const float dsk = Dskip[d];
    __syncthreads();
    const size_t gout = ((size_t)b*LL + l0)*DD + d;
    if (fast) scan2_16<true >(sD, sX, sB, sC, al, d, h, dsk, gout, g);
    else      scan2_16<false>(sD, sX, sB, sC, al, d, h, dsk, gout, g);
}

// ===========================================================================
// FALLBACK (proven 110us, CH=64): k_ln_scan1 + k_combine + k_scan2
// ===========================================================================
template<bool FAST>
__device__ __forceinline__ void dt_scan1_fb(
    const float (*sdt)[20], const unsigned short (*As)[264],
    const float (*sB)[16], const float* wj, float bia,
    const float* al, int d, size_t m0,
    unsigned short* __restrict__ delta,
    float* h, float* dsum)
{
    #pragma unroll 4
    for (int l = 0; l < LCB; ++l) {
        float acc = bia;
        #pragma unroll
        for (int j = 0; j < 16; ++j)
            acc = fmaf(sdt[l][j], wj[j], acc);
        const float sp = (acc > 15.f) ? acc
            : 0.69314718f * log2f(1.f + exp2f(acc * 1.44269504f));
        const unsigned short dbits = f2bf(sp);
        delta[(m0 + l)*DD + d] = dbits;
        const float dl = bf2f(dbits);
        const float xl = bf2f(As[l][d]);
        const float dx = dl * xl;
        *dsum += dl;
        float e[NN];
        if (FAST) pow_tree(exp2f(al[0]*dl), e);
        else {
            #pragma unroll
            for (int n = 0; n < NN; ++n) e[n] = exp2f(al[n]*dl);
        }
        #pragma unroll
        for (int n = 0; n < NN; ++n)
            h[n] = fmaf(e[n], h[n], dx * sB[l][n]);
    }
}

__global__ __launch_bounds__(256) void k_ln_scan1(
    const float* __restrict__ x,
    const float* __restrict__ ln_w,
    const float* __restrict__ ln_b,
    const unsigned short* __restrict__ Wxt,
    const float* __restrict__ dtw,
    const float* __restrict__ dtb,
    const float* __restrict__ A_log,
    unsigned short* __restrict__ xln,
    unsigned short* __restrict__ delta,
    float* __restrict__ Bv,
    float* __restrict__ Cv,
    float* __restrict__ S,
    float* __restrict__ Dsum)
{
    const int t = threadIdx.x;
    const int blk = blockIdx.x;
    const size_t m0 = (size_t)blk * 32;
    const int row = t >> 3, seg = t & 7;
    const size_t grow = m0 + row;

    __shared__ unsigned short As[32][264];
    __shared__ float sdt[32][20];
    __shared__ float sB[32][16];
    __shared__ float slnw[256], slnb[256], sdtb[256];

    {
        const int tt = t & 63;
        if (t < 64)       *(float4*)&slnw[tt*4] = *(const float4*)&ln_w[tt*4];
        else if (t < 128) *(float4*)&slnb[tt*4] = *(const float4*)&ln_b[tt*4];
        else if (t < 192) *(float4*)&sdtb[tt*4] = *(const float4*)&dtb[tt*4];
    }
    float wj[16];
    #pragma unroll
    for (int j = 0; j < 16; ++j) wj[j] = dtw[j*DD + t];
    float al[NN];
    bool fast = true;
    #pragma unroll
    for (int n = 0; n < NN; ++n) {
        al[n] = -expf(A_log[t*NN + n]) * 1.44269504f;
        fast = fast && (fabsf(al[n] - (n+1)*al[0]) <= 1e-3f*fabsf(al[n]) + 1e-6f);
    }
    float v[32];
    #pragma unroll
    for (int i = 0; i < 8; ++i)
        *(float4*)&v[i*4] = *(const float4*)(x + grow*DD + i*32 + seg*4);
    float s = 0.f, q = 0.f;
    #pragma unroll
    for (int i = 0; i < 32; ++i) { s += v[i]; q = fmaf(v[i], v[i], q); }
    #pragma unroll
    for (int o = 1; o < 8; o <<= 1) {
        s += __shfl_xor(s, o);
        q += __shfl_xor(q, o);
    }
    const float mu = s * (1.f/DD);
    const float rs = rsqrtf(q * (1.f/DD) - mu*mu + 1e-5f);
    __syncthreads();
    #pragma unroll
    for (int i = 0; i < 8; ++i) {
        const int c = i*32 + seg*4;
        const float4 wv = *(const float4*)&slnw[c];
        const float4 bv = *(const float4*)&slnb[c];
        unsigned short o16[4];
        o16[0] = f2bf((v[i*4+0]-mu)*rs*wv.x + bv.x);
        o16[1] = f2bf((v[i*4+1]-mu)*rs*wv.y + bv.y);
        o16[2] = f2bf((v[i*4+2]-mu)*rs*wv.z + bv.z);
        o16[3] = f2bf((v[i*4+3]-mu)*rs*wv.w + bv.w);
        *(bf16x4*)&xln[grow*DD + c] = *(bf16x4*)&o16[0];
        *(bf16x4*)&As[row][c]       = *(bf16x4*)&o16[0];
    }
    __syncthreads();
    {
        const int w = t >> 6, lane = t & 63;
        const int cl = lane & 15, rq = lane >> 4;
        const int mh = (w & 1) * 16;
        const int nh = (w >> 1) * 32;
        f32x4 acc0 = {0.f,0.f,0.f,0.f}, acc1 = {0.f,0.f,0.f,0.f};
        #pragma unroll
        for (int k0 = 0; k0 < 256; k0 += 32) {
            const bf16x8 a  = *(const bf16x8*)&As[mh + cl][k0 + rq*8];
            const bf16x8 b0 = *(const bf16x8*)&Wxt[(size_t)(nh + cl)*DD + k0 + rq*8];
            acc0 = __builtin_amdgcn_mfma_f32_16x16x32_bf16(a, b0, acc0, 0, 0, 0);
            if (w < 2) {
                const bf16x8 b1 = *(const bf16x8*)&Wxt[(size_t)(nh + 16 + cl)*DD + k0 + rq*8];
                acc1 = __builtin_amdgcn_mfma_f32_16x16x32_bf16(a, b1, acc1, 0, 0, 0);
            }
        }
        if (w < 2) {
            #pragma unroll
            for (int r = 0; r < 4; ++r) {
                const int rr = mh + rq*4 + r;
                sdt[rr][cl] = acc0[r];
                sB[rr][cl]  = acc1[r];
                Bv[(m0 + rr)*NN + cl] = acc1[r];
            }
        } else {
            #pragma unroll
            for (int r = 0; r < 4; ++r)
                Cv[(m0 + mh + rq*4 + r)*NN + cl] = acc0[r];
        }
    }
    __syncthreads();
    float h[NN];
    #pragma unroll
    for (int n = 0; n < NN; ++n) h[n] = 0.f;
    float dsum = 0.f;
    const float bia = sdtb[t];
    if (fast) dt_scan1_fb<true >(sdt, As, sB, wj, bia, al, t, m0, delta, h, &dsum);
    else      dt_scan1_fb<false>(sdt, As, sB, wj, bia, al, t, m0, delta, h, &dsum);
    const size_t o = (size_t)blk * NN * DD + t;
    #pragma unroll
    for (int n = 0; n < NN; ++n) S[o + n*DD] = h[n];
    Dsum[(size_t)blk*DD + t] = dsum;
}

__global__ __launch_bounds__(256) void k_combine(
    const float* __restrict__ S, const float* __restrict__ Dsum,
    const float* __restrict__ A_log, float* __restrict__ Hin)
{
    const int bi = blockIdx.x;
    const int d = threadIdx.x;
    const int n = bi & 15;
    const int b = bi >> 4;
    const float al = -expf(A_log[d*NN + n]) * 1.44269504f;
    float h = 0.f;
    for (int c0 = 0; c0 < CHB; c0 += 8) {
        float ds8[8], s8[8];
        #pragma unroll
        for (int i = 0; i < 8; ++i) {
            const size_t blk = (size_t)b*CHB + c0 + i;
            ds8[i] = Dsum[blk*DD + d];
            s8[i]  = S[(blk*NN + n)*DD + d];
        }
        #pragma unroll
        for (int i = 0; i < 8; ++i) {
            const size_t blk = (size_t)b*CHB + c0 + i;
            Hin[(blk*NN + n)*DD + d] = h;
            h = fmaf(exp2f(al * ds8[i]), h, s8[i]);
        }
    }
}

template<bool FAST>
__device__ __forceinline__ void scan2_impl_fb(
    const unsigned short (*sD)[264], const unsigned short (*sX)[264],
    const float (*sB)[16], const float (*sC)[16],
    const float* al, int d, float* h, float dsk,
    size_t gout, unsigned short* __restrict__ g)
{
    #pragma unroll 4
    for (int l = 0; l < LCB; ++l) {
        const float dl = bf2f(sD[l][d]);
        const float xl = bf2f(sX[l][d]);
        const float dx = dl * xl;
        float e[NN];
        if (FAST) pow_tree(exp2f(al[0]*dl), e);
        else {
            #pragma unroll
            for (int n = 0; n < NN; ++n) e[n] = exp2f(al[n]*dl);
        }
        float yb[4] = {0.f, 0.f, 0.f, 0.f};
        #pragma unroll
        for (int n = 0; n < NN; ++n) {
            h[n] = fmaf(e[n], h[n], dx * sB[l][n]);
            yb[n & 3] = fmaf(h[n], sC[l][n], yb[n & 3]);
        }
        const float vv = (yb[0]+yb[1]) + (yb[2]+yb[3]) + xl * dsk;
        const float u  = 0.7978845608f * (vv + 0.044715f*vv*vv*vv);
        const float t2 = exp2f(2.8853900818f * u);
        const float th = 1.f - 2.f/(t2 + 1.f);
        g[gout + (size_t)l*DD] = f2bf(0.5f * vv * (1.f + th));
    }
}

__global__ __launch_bounds__(256) void k_scan2(
    const unsigned short* __restrict__ delta,
    const unsigned short* __restrict__ xln,
    const float* __restrict__ Bv,
    const float* __restrict__ Cv,
    const float* __restrict__ A_log,
    const float* __restrict__ Hin,
    const float* __restrict__ Dskip,
    unsigned short* __restrict__ g)
{
    const int blk = blockIdx.x;
    const int c = blk & (CHB-1);
    const int b = blk >> 6;
    const int d = threadIdx.x;
    const int l0 = c * LCB;
    __shared__ unsigned short sD[LCB][264];
    __shared__ unsigned short sX[LCB][264];
    __shared__ float sB[LCB][16], sC[LCB][16];
    {
        const int sr = d >> 3, sc = (d & 7) * 32;
        const size_t gbase = ((size_t)b*LL + l0 + sr)*DD + sc;
        #pragma unroll
        for (int i = 0; i < 4; ++i) {
            *(bf16x8*)&sD[sr][sc + i*8] = *(const bf16x8*)&delta[gbase + i*8];
            *(bf16x8*)&sX[sr][sc + i*8] = *(const bf16x8*)&xln  [gbase + i*8];
        }
        if (d < 128) {
            const int l = d >> 2, qq = (d & 3) * 4;
            *(float4*)&sB[l][qq] = *(const float4*)&Bv[((size_t)b*LL + l0 + l)*NN + qq];
        } else {
            const int dd = d - 128;
            const int l = dd >> 2, qq = (dd & 3) * 4;
            *(float4*)&sC[l][qq] = *(const float4*)&Cv[((size_t)b*LL + l0 + l)*NN + qq];
        }
    }
    float al[NN];
    bool fast = true;
    #pragma unroll
    for (int n = 0; n < NN; ++n) {
        al[n] = -expf(A_log[d*NN + n]) * 1.44269504f;
        fast = fast && (fabsf(al[n] - (n+1)*al[0]) <= 1e-3f*fabsf(al[n]) + 1e-6f);
    }
    float h[NN];
    const size_t ob = (size_t)blk * NN * DD + d;
    #pragma unroll
    for (int n = 0; n < NN; ++n) h[n] = Hin[ob + n*DD];
    const float dsk = Dskip[d];
    __syncthreads();
    const size_t gout = ((size_t)b*LL + l0)*DD + d;
    if (fast) scan2_impl_fb<true >(sD, sX, sB, sC, al, d, h, dsk, gout, g);
    else      scan2_impl_fb<false>(sD, sX, sB, sC, al, d, h, dsk, gout, g);
}

// ---------------------------------------------------------------------------
// GLU GEMM (32768x256 @ 256x512) + bias + sigmoid gate + skip
// ---------------------------------------------------------------------------
__global__ __launch_bounds__(256) void k_glu(
    const unsigned short* __restrict__ g,
    const unsigned short* __restrict__ Wt,
    const float* __restrict__ gb,
    const float* __restrict__ x,
    float* __restrict__ out)
{
    __shared__ unsigned short As[64][40];
    __shared__ unsigned short Bl[64][40];
    __shared__ unsigned short Bh[64][40];
    const int n0 = blockIdx.x * 64;
    const int m0 = blockIdx.y * 64;
    const int t = threadIdx.x;
    const int w = t >> 6, lane = t & 63;
    const int r = t >> 2, q = t & 3;
    const int cl = lane & 15, rq = lane >> 4;
    f32x4 accL[4], accH[4];
    const f32x4 zz = {0.f, 0.f, 0.f, 0.f};
    #pragma unroll
    for (int nf = 0; nf < 4; ++nf) { accL[nf] = zz; accH[nf] = zz; }

    for (int k0 = 0; k0 < 256; k0 += 32) {
        *(bf16x8*)(&As[r][q*8]) = *(const bf16x8*)(&g [(size_t)(m0+r)*DD + k0 + q*8]);
        *(bf16x8*)(&Bl[r][q*8]) = *(const bf16x8*)(&Wt[(size_t)(n0+r)*DD + k0 + q*8]);
        *(bf16x8*)(&Bh[r][q*8]) = *(const bf16x8*)(&Wt[(size_t)(n0+256+r)*DD + k0 + q*8]);
        __syncthreads();
        const bf16x8 a = *(const bf16x8*)(&As[w*16 + cl][rq*8]);
        #pragma unroll
        for (int nf = 0; nf < 4; ++nf) {
            const bf16x8 bl = *(const bf16x8*)(&Bl[nf*16 + cl][rq*8]);
            const bf16x8 bh = *(const bf16x8*)(&Bh[nf*16 + cl][rq*8]);
            accL[nf] = __builtin_amdgcn_mfma_f32_16x16x32_bf16(a, bl, accL[nf], 0, 0, 0);
            accH[nf] = __builtin_amdgcn_mfma_f32_16x16x32_bf16(a, bh, accH[nf], 0, 0, 0);
        }
        __syncthreads();
    }
    #pragma unroll
    for (int nf = 0; nf < 4; ++nf) {
        const int j = n0 + nf*16 + cl;
        const float bL = gb[j];
        const float bH = gb[j + 256];
        #pragma unroll
        for (int rr = 0; rr < 4; ++rr) {
            const int m = m0 + w*16 + rq*4 + rr;
            const float lo = accL[nf][rr] + bL;
            const float hi = accH[nf][rr] + bH;
            const float sg = 1.f / (1.f + exp2f(-1.44269504f * hi));
            out[(size_t)m*DD + j] = lo * sg + x[(size_t)m*DD + j];
        }
    }
}

extern "C" void kernel_launch(void* const* d_in, const int* in_sizes, int n_in,
                              void* d_out, int out_size, void* d_ws, size_t ws_size,
                              hipStream_t stream)
{
    const float* x    = (const float*)d_in[0];
    const float* ln_w = (const float*)d_in[1];
    const float* ln_b = (const float*)d_in[2];
    const float* xpw  = (const float*)d_in[3];
    const float* dtw  = (const float*)d_in[4];
    const float* dtb  = (const float*)d_in[5];
    const float* alog = (const float*)d_in[6];
    const float* dsk  = (const float*)d_in[7];
    const float* gw   = (const float*)d_in[8];
    const float* gb   = (const float*)d_in[9];
    float* out = (float*)d_out;

    char* ws = (char*)d_ws;
    size_t off = 0;
    auto alloc = [&](size_t bytes) {
        char* p = ws + off; off += (bytes + 255) & ~(size_t)255; return p;
    };
    // Common buffers
    unsigned short* xln    = (unsigned short*)alloc((size_t)BB*LL*DD*2);
    unsigned short* deltaG = (unsigned short*)alloc((size_t)BB*LL*DD*2);
    float*          Bvp    = (float*)         alloc((size_t)BB*LL*NN*4);
    float*          Cvp    = (float*)         alloc((size_t)BB*LL*NN*4);
    unsigned short* Wt     = (unsigned short*)alloc((size_t)512*256*2);
    unsigned short* Wxt    = (unsigned short*)alloc((size_t)64*256*2);
    unsigned short* g      = deltaG;   // scan2 writes g over delta (staged first)

    // CH=128 layout (primary): S 33.5MB + Dsum 2.1 + Hin 33.5
    size_t off128 = off;
    auto alloc128 = [&](size_t bytes) {
        char* p = ws + off128; off128 += (bytes + 255) & ~(size_t)255; return p;
    };
    float* S128    = (float*)alloc128((size_t)BB*CH2*NN*DD*4);
    float* Dsum128 = (float*)alloc128((size_t)BB*CH2*DD*4);
    float* Hin128  = (float*)alloc128((size_t)BB*CH2*NN*DD*4);
    const bool use128 = (off128 <= ws_size);

    k_prep<<<144, 256, 0, stream>>>(xpw, gw, Wxt, Wt);

    if (use128) {
        k_ln_scan1_16<<<BB*CH2, 256, 0, stream>>>(x, ln_w, ln_b, Wxt, dtw, dtb, alog,
                                                  xln, deltaG, Bvp, Cvp, S128, Dsum128);
        k_combine_128<<<256, 256, 0, stream>>>(S128, Dsum128, alog, Hin128);
        k_scan2_16<<<BB*CH2, 256, 0, stream>>>(deltaG, xln, Bvp, Cvp, alog, Hin128, dsk, g);
    } else {
        float* S    = (float*)alloc((size_t)BB*CHB*NN*DD*4);
        float* Dsum = (float*)alloc((size_t)BB*CHB*DD*4);
        float* Hin  = (float*)alloc((size_t)BB*CHB*NN*DD*4);
        k_ln_scan1<<<BB*CHB, 256, 0, stream>>>(x, ln_w, ln_b, Wxt, dtw, dtb, alog,
                                               xln, deltaG, Bvp, Cvp, S, Dsum);
        k_combine<<<256, 256, 0, stream>>>(S, Dsum, alog, Hin);
        k_scan2<<<BB*CHB, 256, 0, stream>>>(deltaG, xln, Bvp, Cvp, alog, Hin, dsk, g);
    }

    k_glu<<<dim3(4, 512), 256, 0, stream>>>(g, Wt, gb, x, out);
}

// Round 14
// 113.172 us; speedup vs baseline: 2.3145x; 1.0466x over previous
//
#include <hip/hip_runtime.h>
#include <hip/hip_bf16.h>

#define BB 16
#define LL 2048
#define DD 256
#define NN 16
#define RR 16
#define CH 64
#define LC (LL/CH)   /* 32 */

static __device__ __forceinline__ float bf2f(unsigned short u) {
    return __uint_as_float(((unsigned)u) << 16);
}
static __device__ __forceinline__ unsigned short f2bf(float f) {
    unsigned u = __float_as_uint(f);
    u += 0x7FFFu + ((u >> 16) & 1u);
    return (unsigned short)(u >> 16);
}

typedef __attribute__((ext_vector_type(8))) short bf16x8;
typedef __attribute__((ext_vector_type(4))) short bf16x4;
typedef __attribute__((ext_vector_type(4))) float f32x4;

// e[n] = E^(n+1), depth-4 product tree
static __device__ __forceinline__ void pow_tree(float E, float* e) {
    e[0] = E;
    e[1] = E * E;
    e[2] = e[1] * E;
    e[3] = e[1] * e[1];
    e[4] = e[3] * e[0];  e[5] = e[3] * e[1];  e[6] = e[3] * e[2];  e[7] = e[3] * e[3];
    e[8] = e[7] * e[0];  e[9] = e[7] * e[1];  e[10] = e[7] * e[2]; e[11] = e[7] * e[3];
    e[12] = e[7] * e[4]; e[13] = e[7] * e[5]; e[14] = e[7] * e[6]; e[15] = e[7] * e[7];
}

// ---------------------------------------------------------------------------
// prep: bid<16 -> Wxt (xw^T bf16, 48->64 pad); bid 16..143 -> Wt (glu_w^T);
// bid 144 -> Dwt (dtw^T, 256x32 bf16, K zero-padded 16->32)
// ---------------------------------------------------------------------------
__global__ __launch_bounds__(256) void k_prep(
    const float* __restrict__ xw, const float* __restrict__ gw,
    const float* __restrict__ dtw,
    unsigned short* __restrict__ Wxt, unsigned short* __restrict__ Wt,
    unsigned short* __restrict__ Dwt)
{
    __shared__ unsigned short s[32][33];
    const int bid = blockIdx.x;
    const int t = threadIdx.x;
    if (bid < 16) {
        const int idx = bid * 256 + t;
        const int n  = idx >> 6;
        const int k0 = (idx & 63) * 4;
        #pragma unroll
        for (int i = 0; i < 4; ++i) {
            float v = (n < 48) ? xw[(size_t)(k0 + i) * 48 + n] : 0.f;
            Wxt[(size_t)n * DD + k0 + i] = f2bf(v);
        }
    } else if (bid < 144) {
        const int bb = bid - 16;
        const int bx = bb & 15, by = bb >> 4;
        const int r = t >> 5, cc = t & 31;
        #pragma unroll
        for (int i = 0; i < 4; ++i)
            s[r + 8*i][cc] = f2bf(gw[(size_t)(by*32 + r + 8*i)*512 + bx*32 + cc]);
        __syncthreads();
        #pragma unroll
        for (int i = 0; i < 4; ++i)
            Wt[(size_t)(bx*32 + r + 8*i)*256 + by*32 + cc] = s[cc][r + 8*i];
    } else {
        // Dwt[n][k] = dtw[k][n] for k<16, else 0. thread t = column n.
        unsigned short r32[32];
        #pragma unroll
        for (int k = 0; k < 16; ++k) r32[k] = f2bf(dtw[(size_t)k*DD + t]);
        #pragma unroll
        for (int k = 16; k < 32; ++k) r32[k] = 0;
        #pragma unroll
        for (int i = 0; i < 4; ++i)
            *(bf16x8*)&Dwt[(size_t)t*32 + i*8] = *(bf16x8*)&r32[i*8];
    }
}

// ---------------------------------------------------------------------------
// k_ln_scan1: LN -> x_proj MFMA -> dt_proj MFMA (K-pad 32) + softplus ->
// scan pass 1. Per scan step: 1 u16 (sDel) + 1 u16 (As) + 4 b128 (sB) reads.
// ---------------------------------------------------------------------------
template<bool FAST>
__device__ __forceinline__ void scan1_loop(
    const unsigned short (*sDel)[264], const unsigned short (*As)[264],
    const float (*sB)[20], const float* al, int t,
    float* h, float* dsum)
{
    #pragma unroll 4
    for (int l = 0; l < LC; ++l) {
        const float dl = bf2f(sDel[l][t]);
        const float xl = bf2f(As[l][t]);
        const float dx = dl * xl;
        *dsum += dl;
        float e[NN];
        if (FAST) pow_tree(exp2f(al[0]*dl), e);
        else {
            #pragma unroll
            for (int n = 0; n < NN; ++n) e[n] = exp2f(al[n]*dl);
        }
        const float4 B0 = *(const float4*)&sB[l][0];
        const float4 B1 = *(const float4*)&sB[l][4];
        const float4 B2 = *(const float4*)&sB[l][8];
        const float4 B3 = *(const float4*)&sB[l][12];
        const float bb[16] = {B0.x,B0.y,B0.z,B0.w, B1.x,B1.y,B1.z,B1.w,
                              B2.x,B2.y,B2.z,B2.w, B3.x,B3.y,B3.z,B3.w};
        #pragma unroll
        for (int n = 0; n < NN; ++n)
            h[n] = fmaf(e[n], h[n], dx * bb[n]);
    }
}

__global__ __launch_bounds__(256) void k_ln_scan1(
    const float* __restrict__ x,
    const float* __restrict__ ln_w,
    const float* __restrict__ ln_b,
    const unsigned short* __restrict__ Wxt,
    const unsigned short* __restrict__ Dwt,
    const float* __restrict__ dtb,
    const float* __restrict__ A_log,
    unsigned short* __restrict__ xln,
    unsigned short* __restrict__ delta,
    float* __restrict__ Bv,
    float* __restrict__ Cv,
    float* __restrict__ S,
    float* __restrict__ Dsum)
{
    const int t = threadIdx.x;
    const int blk = blockIdx.x;
    const size_t m0 = (size_t)blk * LC;
    const int row = t >> 3, seg = t & 7;
    const size_t grow = m0 + row;

    __shared__ unsigned short As[LC][264];     // xln tile
    __shared__ unsigned short sDel[LC][264];   // delta tile (bf16)
    __shared__ unsigned short sdt16[LC][40];   // dt MFMA A-operand (bf16, K-pad)
    __shared__ float sB[LC][20];
    __shared__ float slnw[256], slnb[256], sdtb[256];

    // ---- stage small vectors + zero-fill sdt16 K-pad columns
    {
        const int tt = t & 63;
        if (t < 64)       *(float4*)&slnw[tt*4] = *(const float4*)&ln_w[tt*4];
        else if (t < 128) *(float4*)&slnb[tt*4] = *(const float4*)&ln_b[tt*4];
        else if (t < 192) *(float4*)&sdtb[tt*4] = *(const float4*)&dtb[tt*4];
        if (t < 64) {
            const bf16x8 z = {0,0,0,0,0,0,0,0};
            *(bf16x8*)&sdt16[t >> 1][16 + (t & 1)*8] = z;
        }
    }
    float al[NN];
    bool fast = true;
    #pragma unroll
    for (int n = 0; n < NN; ++n) {
        al[n] = -expf(A_log[t*NN + n]) * 1.44269504f;
        fast = fast && (fabsf(al[n] - (n+1)*al[0]) <= 1e-3f*fabsf(al[n]) + 1e-6f);
    }

    // ---- LN (8 threads/row, 32 floats/thread, strided)
    float v[32];
    #pragma unroll
    for (int i = 0; i < 8; ++i)
        *(float4*)&v[i*4] = *(const float4*)(x + grow*DD + i*32 + seg*4);
    float s = 0.f, q = 0.f;
    #pragma unroll
    for (int i = 0; i < 32; ++i) { s += v[i]; q = fmaf(v[i], v[i], q); }
    #pragma unroll
    for (int o = 1; o < 8; o <<= 1) {
        s += __shfl_xor(s, o);
        q += __shfl_xor(q, o);
    }
    const float mu = s * (1.f/DD);
    const float rs = rsqrtf(q * (1.f/DD) - mu*mu + 1e-5f);
    __syncthreads();
    #pragma unroll
    for (int i = 0; i < 8; ++i) {
        const int c = i*32 + seg*4;
        const float4 wv = *(const float4*)&slnw[c];
        const float4 bv = *(const float4*)&slnb[c];
        unsigned short o16[4];
        o16[0] = f2bf((v[i*4+0]-mu)*rs*wv.x + bv.x);
        o16[1] = f2bf((v[i*4+1]-mu)*rs*wv.y + bv.y);
        o16[2] = f2bf((v[i*4+2]-mu)*rs*wv.z + bv.z);
        o16[3] = f2bf((v[i*4+3]-mu)*rs*wv.w + bv.w);
        *(bf16x4*)&xln[grow*DD + c] = *(bf16x4*)&o16[0];
        *(bf16x4*)&As[row][c]       = *(bf16x4*)&o16[0];
    }
    __syncthreads();

    const int w = t >> 6, lane = t & 63;
    const int cl = lane & 15, rq = lane >> 4;

    // ---- x_proj MFMA: (32x256)@(256x48) -> sdt16(bf16) | sB+Bv | Cv
    {
        const int mh = (w & 1) * 16;
        const int nh = (w >> 1) * 32;
        f32x4 acc0 = {0.f,0.f,0.f,0.f}, acc1 = {0.f,0.f,0.f,0.f};
        #pragma unroll
        for (int k0 = 0; k0 < 256; k0 += 32) {
            const bf16x8 a  = *(const bf16x8*)&As[mh + cl][k0 + rq*8];
            const bf16x8 b0 = *(const bf16x8*)&Wxt[(size_t)(nh + cl)*DD + k0 + rq*8];
            acc0 = __builtin_amdgcn_mfma_f32_16x16x32_bf16(a, b0, acc0, 0, 0, 0);
            if (w < 2) {
                const bf16x8 b1 = *(const bf16x8*)&Wxt[(size_t)(nh + 16 + cl)*DD + k0 + rq*8];
                acc1 = __builtin_amdgcn_mfma_f32_16x16x32_bf16(a, b1, acc1, 0, 0, 0);
            }
        }
        if (w < 2) {
            #pragma unroll
            for (int r = 0; r < 4; ++r) {
                const int rr = mh + rq*4 + r;
                sdt16[rr][cl] = f2bf(acc0[r]);
                sB[rr][cl]    = acc1[r];
                Bv[(m0 + rr)*NN + cl] = acc1[r];
            }
        } else {
            #pragma unroll
            for (int r = 0; r < 4; ++r)
                Cv[(m0 + mh + rq*4 + r)*NN + cl] = acc0[r];
        }
    }
    __syncthreads();

    // ---- dt_proj MFMA: (32x32K)@(32Kx256) -> softplus -> sDel + global delta
    {
        const int mh = (w & 1) * 16;
        const int nbase = (w >> 1) * 8;          // 8 n-tiles per wave
        const bf16x8 a = *(const bf16x8*)&sdt16[mh + cl][rq*8];
        #pragma unroll
        for (int nt = 0; nt < 8; ++nt) {
            const int n0 = (nbase + nt) * 16;
            const bf16x8 b = *(const bf16x8*)&Dwt[(size_t)(n0 + cl)*32 + rq*8];
            f32x4 acc = {0.f,0.f,0.f,0.f};
            acc = __builtin_amdgcn_mfma_f32_16x16x32_bf16(a, b, acc, 0, 0, 0);
            const float bia = sdtb[n0 + cl];
            #pragma unroll
            for (int r = 0; r < 4; ++r) {
                const float ac = acc[r] + bia;
                const float sp = (ac > 15.f) ? ac
                    : 0.69314718f * log2f(1.f + exp2f(ac * 1.44269504f));
                const unsigned short db = f2bf(sp);
                const int rr = mh + rq*4 + r;
                sDel[rr][n0 + cl] = db;
                delta[(m0 + rr)*DD + n0 + cl] = db;
            }
        }
    }
    __syncthreads();

    // ---- scan pass 1 (thread t = column d)
    float h[NN];
    #pragma unroll
    for (int n = 0; n < NN; ++n) h[n] = 0.f;
    float dsum = 0.f;
    if (fast) scan1_loop<true >(sDel, As, sB, al, t, h, &dsum);
    else      scan1_loop<false>(sDel, As, sB, al, t, h, &dsum);
    const size_t o = (size_t)blk * NN * DD + t;
    #pragma unroll
    for (int n = 0; n < NN; ++n) S[o + n*DD] = h[n];
    Dsum[(size_t)blk*DD + t] = dsum;
}

// ---------------------------------------------------------------------------
// combine: fold over 64 chunks -> Hin (8-deep load batching)
// ---------------------------------------------------------------------------
__global__ __launch_bounds__(256) void k_combine(
    const float* __restrict__ S, const float* __restrict__ Dsum,
    const float* __restrict__ A_log, float* __restrict__ Hin)
{
    const int bi = blockIdx.x;
    const int d = threadIdx.x;
    const int n = bi & 15;
    const int b = bi >> 4;
    const float al = -expf(A_log[d*NN + n]) * 1.44269504f;
    float h = 0.f;
    for (int c0 = 0; c0 < CH; c0 += 8) {
        float ds8[8], s8[8];
        #pragma unroll
        for (int i = 0; i < 8; ++i) {
            const size_t blk = (size_t)b*CH + c0 + i;
            ds8[i] = Dsum[blk*DD + d];
            s8[i]  = S[(blk*NN + n)*DD + d];
        }
        #pragma unroll
        for (int i = 0; i < 8; ++i) {
            const size_t blk = (size_t)b*CH + c0 + i;
            Hin[(blk*NN + n)*DD + d] = h;
            h = fmaf(exp2f(al * ds8[i]), h, s8[i]);
        }
    }
}

// ---------------------------------------------------------------------------
// scan pass 2 — LDS-staged, float4 B/C reads, produces g = gelu(y) (over delta)
// ---------------------------------------------------------------------------
template<bool FAST>
__device__ __forceinline__ void scan2_loop(
    const unsigned short (*sD)[264], const unsigned short (*sX)[264],
    const float (*sB)[20], const float (*sC)[20],
    const float* al, int d, float* h, float dsk,
    size_t gout, unsigned short* __restrict__ g)
{
    #pragma unroll 4
    for (int l = 0; l < LC; ++l) {
        const float dl = bf2f(sD[l][d]);
        const float xl = bf2f(sX[l][d]);
        const float dx = dl * xl;
        float e[NN];
        if (FAST) pow_tree(exp2f(al[0]*dl), e);
        else {
            #pragma unroll
            for (int n = 0; n < NN; ++n) e[n] = exp2f(al[n]*dl);
        }
        const float4 B0 = *(const float4*)&sB[l][0];
        const float4 B1 = *(const float4*)&sB[l][4];
        const float4 B2 = *(const float4*)&sB[l][8];
        const float4 B3 = *(const float4*)&sB[l][12];
        const float bb[16] = {B0.x,B0.y,B0.z,B0.w, B1.x,B1.y,B1.z,B1.w,
                              B2.x,B2.y,B2.z,B2.w, B3.x,B3.y,B3.z,B3.w};
        const float4 C0 = *(const float4*)&sC[l][0];
        const float4 C1 = *(const float4*)&sC[l][4];
        const float4 C2 = *(const float4*)&sC[l][8];
        const float4 C3 = *(const float4*)&sC[l][12];
        const float cc[16] = {C0.x,C0.y,C0.z,C0.w, C1.x,C1.y,C1.z,C1.w,
                              C2.x,C2.y,C2.z,C2.w, C3.x,C3.y,C3.z,C3.w};
        float yb[4] = {0.f, 0.f, 0.f, 0.f};
        #pragma unroll
        for (int n = 0; n < NN; ++n) {
            h[n] = fmaf(e[n], h[n], dx * bb[n]);
            yb[n & 3] = fmaf(h[n], cc[n], yb[n & 3]);
        }
        const float vv = (yb[0]+yb[1]) + (yb[2]+yb[3]) + xl * dsk;
        const float u  = 0.7978845608f * (vv + 0.044715f*vv*vv*vv);
        const float t2 = exp2f(2.8853900818f * u);
        const float th = 1.f - 2.f/(t2 + 1.f);
        g[gout + (size_t)l*DD] = f2bf(0.5f * vv * (1.f + th));
    }
}

__global__ __launch_bounds__(256) void k_scan2(
    const unsigned short* __restrict__ delta,
    const unsigned short* __restrict__ xln,
    const float* __restrict__ Bv,
    const float* __restrict__ Cv,
    const float* __restrict__ A_log,
    const float* __restrict__ Hin,
    const float* __restrict__ Dskip,
    unsigned short* __restrict__ g)
{
    const int blk = blockIdx.x;
    const int c = blk & (CH-1);
    const int b = blk >> 6;
    const int d = threadIdx.x;
    const int l0 = c * LC;
    __shared__ unsigned short sD[LC][264];
    __shared__ unsigned short sX[LC][264];
    __shared__ float sB[LC][20], sC[LC][20];
    {
        const int sr = d >> 3, sc = (d & 7) * 32;
        const size_t gbase = ((size_t)b*LL + l0 + sr)*DD + sc;
        #pragma unroll
        for (int i = 0; i < 4; ++i) {
            *(bf16x8*)&sD[sr][sc + i*8] = *(const bf16x8*)&delta[gbase + i*8];
            *(bf16x8*)&sX[sr][sc + i*8] = *(const bf16x8*)&xln  [gbase + i*8];
        }
        if (d < 128) {
            const int l = d >> 2, qq = (d & 3) * 4;
            *(float4*)&sB[l][qq] = *(const float4*)&Bv[((size_t)b*LL + l0 + l)*NN + qq];
        } else {
            const int dd = d - 128;
            const int l = dd >> 2, qq = (dd & 3) * 4;
            *(float4*)&sC[l][qq] = *(const float4*)&Cv[((size_t)b*LL + l0 + l)*NN + qq];
        }
    }
    float al[NN];
    bool fast = true;
    #pragma unroll
    for (int n = 0; n < NN; ++n) {
        al[n] = -expf(A_log[d*NN + n]) * 1.44269504f;
        fast = fast && (fabsf(al[n] - (n+1)*al[0]) <= 1e-3f*fabsf(al[n]) + 1e-6f);
    }
    float h[NN];
    const size_t ob = (size_t)blk * NN * DD + d;
    #pragma unroll
    for (int n = 0; n < NN; ++n) h[n] = Hin[ob + n*DD];
    const float dsk = Dskip[d];
    __syncthreads();
    const size_t gout = ((size_t)b*LL + l0)*DD + d;
    if (fast) scan2_loop<true >(sD, sX, sB, sC, al, d, h, dsk, gout, g);
    else      scan2_loop<false>(sD, sX, sB, sC, al, d, h, dsk, gout, g);
}

// ---------------------------------------------------------------------------
// GLU GEMM (32768x256 @ 256x512) + bias + sigmoid gate + skip
// ---------------------------------------------------------------------------
__global__ __launch_bounds__(256) void k_glu(
    const unsigned short* __restrict__ g,
    const unsigned short* __restrict__ Wt,
    const float* __restrict__ gb,
    const float* __restrict__ x,
    float* __restrict__ out)
{
    __shared__ unsigned short As[64][40];
    __shared__ unsigned short Bl[64][40];
    __shared__ unsigned short Bh[64][40];
    const int n0 = blockIdx.x * 64;
    const int m0 = blockIdx.y * 64;
    const int t = threadIdx.x;
    const int w = t >> 6, lane = t & 63;
    const int r = t >> 2, q = t & 3;
    const int cl = lane & 15, rq = lane >> 4;
    f32x4 accL[4], accH[4];
    const f32x4 zz = {0.f, 0.f, 0.f, 0.f};
    #pragma unroll
    for (int nf = 0; nf < 4; ++nf) { accL[nf] = zz; accH[nf] = zz; }

    for (int k0 = 0; k0 < 256; k0 += 32) {
        *(bf16x8*)(&As[r][q*8]) = *(const bf16x8*)(&g [(size_t)(m0+r)*DD + k0 + q*8]);
        *(bf16x8*)(&Bl[r][q*8]) = *(const bf16x8*)(&Wt[(size_t)(n0+r)*DD + k0 + q*8]);
        *(bf16x8*)(&Bh[r][q*8]) = *(const bf16x8*)(&Wt[(size_t)(n0+256+r)*DD + k0 + q*8]);
        __syncthreads();
        const bf16x8 a = *(const bf16x8*)(&As[w*16 + cl][rq*8]);
        #pragma unroll
        for (int nf = 0; nf < 4; ++nf) {
            const bf16x8 bl = *(const bf16x8*)(&Bl[nf*16 + cl][rq*8]);
            const bf16x8 bh = *(const bf16x8*)(&Bh[nf*16 + cl][rq*8]);
            accL[nf] = __builtin_amdgcn_mfma_f32_16x16x32_bf16(a, bl, accL[nf], 0, 0, 0);
            accH[nf] = __builtin_amdgcn_mfma_f32_16x16x32_bf16(a, bh, accH[nf], 0, 0, 0);
        }
        __syncthreads();
    }
    #pragma unroll
    for (int nf = 0; nf < 4; ++nf) {
        const int j = n0 + nf*16 + cl;
        const float bL = gb[j];
        const float bH = gb[j + 256];
        #pragma unroll
        for (int rr = 0; rr < 4; ++rr) {
            const int m = m0 + w*16 + rq*4 + rr;
            const float lo = accL[nf][rr] + bL;
            const float hi = accH[nf][rr] + bH;
            const float sg = 1.f / (1.f + exp2f(-1.44269504f * hi));
            out[(size_t)m*DD + j] = lo * sg + x[(size_t)m*DD + j];
        }
    }
}

extern "C" void kernel_launch(void* const* d_in, const int* in_sizes, int n_in,
                              void* d_out, int out_size, void* d_ws, size_t ws_size,
                              hipStream_t stream)
{
    const float* x    = (const float*)d_in[0];
    const float* ln_w = (const float*)d_in[1];
    const float* ln_b = (const float*)d_in[2];
    const float* xpw  = (const float*)d_in[3];
    const float* dtw  = (const float*)d_in[4];
    const float* dtb  = (const float*)d_in[5];
    const float* alog = (const float*)d_in[6];
    const float* dsk  = (const float*)d_in[7];
    const float* gw   = (const float*)d_in[8];
    const float* gb   = (const float*)d_in[9];
    float* out = (float*)d_out;

    char* ws = (char*)d_ws;
    size_t off = 0;
    auto alloc = [&](size_t bytes) {
        char* p = ws + off; off += (bytes + 255) & ~(size_t)255; return p;
    };
    unsigned short* xln    = (unsigned short*)alloc((size_t)BB*LL*DD*2);
    unsigned short* deltaG = (unsigned short*)alloc((size_t)BB*LL*DD*2);
    float*          Bvp    = (float*)         alloc((size_t)BB*LL*NN*4);
    float*          Cvp    = (float*)         alloc((size_t)BB*LL*NN*4);
    float*          S      = (float*)         alloc((size_t)BB*CH*NN*DD*4);
    float*          Dsum   = (float*)         alloc((size_t)BB*CH*DD*4);
    float*          Hin    = (float*)         alloc((size_t)BB*CH*NN*DD*4);
    unsigned short* Wt     = (unsigned short*)alloc((size_t)512*256*2);
    unsigned short* Wxt    = (unsigned short*)alloc((size_t)64*256*2);
    unsigned short* Dwt    = (unsigned short*)alloc((size_t)256*32*2);
    unsigned short* g      = deltaG;   // scan2 overwrites delta (staged first)

    k_prep<<<145, 256, 0, stream>>>(xpw, gw, dtw, Wxt, Wt, Dwt);
    k_ln_scan1<<<BB*CH, 256, 0, stream>>>(x, ln_w, ln_b, Wxt, Dwt, dtb, alog,
                                          xln, deltaG, Bvp, Cvp, S, Dsum);
    k_combine<<<256, 256, 0, stream>>>(S, Dsum, alog, Hin);
    k_scan2<<<BB*CH, 256, 0, stream>>>(deltaG, xln, Bvp, Cvp, alog, Hin, dsk, g);
    k_glu<<<dim3(4, 512), 256, 0, stream>>>(g, Wt, gb, x, out);
}

// Round 15
// 110.901 us; speedup vs baseline: 2.3619x; 1.0205x over previous
//
#include <hip/hip_runtime.h>
#include <hip/hip_bf16.h>

#define BB 16
#define LL 2048
#define DD 256
#define NN 16
#define RR 16
#define CH 64
#define LC (LL/CH)   /* 32 */

static __device__ __forceinline__ float bf2f(unsigned short u) {
    return __uint_as_float(((unsigned)u) << 16);
}
static __device__ __forceinline__ unsigned short f2bf(float f) {
    unsigned u = __float_as_uint(f);
    u += 0x7FFFu + ((u >> 16) & 1u);
    return (unsigned short)(u >> 16);
}

typedef __attribute__((ext_vector_type(8))) short bf16x8;
typedef __attribute__((ext_vector_type(4))) short bf16x4;
typedef __attribute__((ext_vector_type(4))) float f32x4;

// e[n] = E^(n+1), depth-4 product tree
static __device__ __forceinline__ void pow_tree(float E, float* e) {
    e[0] = E;
    e[1] = E * E;
    e[2] = e[1] * E;
    e[3] = e[1] * e[1];
    e[4] = e[3] * e[0];  e[5] = e[3] * e[1];  e[6] = e[3] * e[2];  e[7] = e[3] * e[3];
    e[8] = e[7] * e[0];  e[9] = e[7] * e[1];  e[10] = e[7] * e[2]; e[11] = e[7] * e[3];
    e[12] = e[7] * e[4]; e[13] = e[7] * e[5]; e[14] = e[7] * e[6]; e[15] = e[7] * e[7];
}

// ---------------------------------------------------------------------------
// prep: bid<16 -> Wxt (xw^T bf16, 48->64 pad); bid 16..143 -> Wt (glu_w^T);
// bid 144 -> Dwt (dtw^T, 256x32 bf16, K zero-padded 16->32)
// ---------------------------------------------------------------------------
__global__ __launch_bounds__(256) void k_prep(
    const float* __restrict__ xw, const float* __restrict__ gw,
    const float* __restrict__ dtw,
    unsigned short* __restrict__ Wxt, unsigned short* __restrict__ Wt,
    unsigned short* __restrict__ Dwt)
{
    __shared__ unsigned short s[32][33];
    const int bid = blockIdx.x;
    const int t = threadIdx.x;
    if (bid < 16) {
        const int idx = bid * 256 + t;
        const int n  = idx >> 6;
        const int k0 = (idx & 63) * 4;
        #pragma unroll
        for (int i = 0; i < 4; ++i) {
            float v = (n < 48) ? xw[(size_t)(k0 + i) * 48 + n] : 0.f;
            Wxt[(size_t)n * DD + k0 + i] = f2bf(v);
        }
    } else if (bid < 144) {
        const int bb = bid - 16;
        const int bx = bb & 15, by = bb >> 4;
        const int r = t >> 5, cc = t & 31;
        #pragma unroll
        for (int i = 0; i < 4; ++i)
            s[r + 8*i][cc] = f2bf(gw[(size_t)(by*32 + r + 8*i)*512 + bx*32 + cc]);
        __syncthreads();
        #pragma unroll
        for (int i = 0; i < 4; ++i)
            Wt[(size_t)(bx*32 + r + 8*i)*256 + by*32 + cc] = s[cc][r + 8*i];
    } else {
        // Dwt[n][k] = dtw[k][n] for k<16, else 0. thread t = column n.
        unsigned short r32[32];
        #pragma unroll
        for (int k = 0; k < 16; ++k) r32[k] = f2bf(dtw[(size_t)k*DD + t]);
        #pragma unroll
        for (int k = 16; k < 32; ++k) r32[k] = 0;
        #pragma unroll
        for (int i = 0; i < 4; ++i)
            *(bf16x8*)&Dwt[(size_t)t*32 + i*8] = *(bf16x8*)&r32[i*8];
    }
}

// ---------------------------------------------------------------------------
// k_ln_scan1: LN -> x_proj MFMA -> dt_proj MFMA (K-pad 32) + softplus ->
// scan pass 1. S stored as bf16 (halves the biggest intermediate).
// ---------------------------------------------------------------------------
template<bool FAST>
__device__ __forceinline__ void scan1_loop(
    const unsigned short (*sDel)[264], const unsigned short (*As)[264],
    const float (*sB)[20], const float* al, int t,
    float* h, float* dsum)
{
    #pragma unroll 4
    for (int l = 0; l < LC; ++l) {
        const float dl = bf2f(sDel[l][t]);
        const float xl = bf2f(As[l][t]);
        const float dx = dl * xl;
        *dsum += dl;
        float e[NN];
        if (FAST) pow_tree(exp2f(al[0]*dl), e);
        else {
            #pragma unroll
            for (int n = 0; n < NN; ++n) e[n] = exp2f(al[n]*dl);
        }
        const float4 B0 = *(const float4*)&sB[l][0];
        const float4 B1 = *(const float4*)&sB[l][4];
        const float4 B2 = *(const float4*)&sB[l][8];
        const float4 B3 = *(const float4*)&sB[l][12];
        const float bb[16] = {B0.x,B0.y,B0.z,B0.w, B1.x,B1.y,B1.z,B1.w,
                              B2.x,B2.y,B2.z,B2.w, B3.x,B3.y,B3.z,B3.w};
        #pragma unroll
        for (int n = 0; n < NN; ++n)
            h[n] = fmaf(e[n], h[n], dx * bb[n]);
    }
}

__global__ __launch_bounds__(256) void k_ln_scan1(
    const float* __restrict__ x,
    const float* __restrict__ ln_w,
    const float* __restrict__ ln_b,
    const unsigned short* __restrict__ Wxt,
    const unsigned short* __restrict__ Dwt,
    const float* __restrict__ dtb,
    const float* __restrict__ A_log,
    unsigned short* __restrict__ xln,
    unsigned short* __restrict__ delta,
    float* __restrict__ Bv,
    float* __restrict__ Cv,
    unsigned short* __restrict__ S,     // bf16
    float* __restrict__ Dsum)
{
    const int t = threadIdx.x;
    const int blk = blockIdx.x;
    const size_t m0 = (size_t)blk * LC;
    const int row = t >> 3, seg = t & 7;
    const size_t grow = m0 + row;

    __shared__ unsigned short As[LC][264];     // xln tile
    __shared__ unsigned short sDel[LC][264];   // delta tile (bf16)
    __shared__ unsigned short sdt16[LC][40];   // dt MFMA A-operand (bf16, K-pad)
    __shared__ float sB[LC][20];
    __shared__ float slnw[256], slnb[256], sdtb[256];

    // ---- stage small vectors + zero-fill sdt16 K-pad columns
    {
        const int tt = t & 63;
        if (t < 64)       *(float4*)&slnw[tt*4] = *(const float4*)&ln_w[tt*4];
        else if (t < 128) *(float4*)&slnb[tt*4] = *(const float4*)&ln_b[tt*4];
        else if (t < 192) *(float4*)&sdtb[tt*4] = *(const float4*)&dtb[tt*4];
        if (t < 64) {
            const bf16x8 z = {0,0,0,0,0,0,0,0};
            *(bf16x8*)&sdt16[t >> 1][16 + (t & 1)*8] = z;
        }
    }
    float al[NN];
    bool fast = true;
    #pragma unroll
    for (int n = 0; n < NN; ++n) {
        al[n] = -expf(A_log[t*NN + n]) * 1.44269504f;
        fast = fast && (fabsf(al[n] - (n+1)*al[0]) <= 1e-3f*fabsf(al[n]) + 1e-6f);
    }

    // ---- LN (8 threads/row, 32 floats/thread, strided)
    float v[32];
    #pragma unroll
    for (int i = 0; i < 8; ++i)
        *(float4*)&v[i*4] = *(const float4*)(x + grow*DD + i*32 + seg*4);
    float s = 0.f, q = 0.f;
    #pragma unroll
    for (int i = 0; i < 32; ++i) { s += v[i]; q = fmaf(v[i], v[i], q); }
    #pragma unroll
    for (int o = 1; o < 8; o <<= 1) {
        s += __shfl_xor(s, o);
        q += __shfl_xor(q, o);
    }
    const float mu = s * (1.f/DD);
    const float rs = rsqrtf(q * (1.f/DD) - mu*mu + 1e-5f);
    __syncthreads();
    #pragma unroll
    for (int i = 0; i < 8; ++i) {
        const int c = i*32 + seg*4;
        const float4 wv = *(const float4*)&slnw[c];
        const float4 bv = *(const float4*)&slnb[c];
        unsigned short o16[4];
        o16[0] = f2bf((v[i*4+0]-mu)*rs*wv.x + bv.x);
        o16[1] = f2bf((v[i*4+1]-mu)*rs*wv.y + bv.y);
        o16[2] = f2bf((v[i*4+2]-mu)*rs*wv.z + bv.z);
        o16[3] = f2bf((v[i*4+3]-mu)*rs*wv.w + bv.w);
        *(bf16x4*)&xln[grow*DD + c] = *(bf16x4*)&o16[0];
        *(bf16x4*)&As[row][c]       = *(bf16x4*)&o16[0];
    }
    __syncthreads();

    const int w = t >> 6, lane = t & 63;
    const int cl = lane & 15, rq = lane >> 4;

    // ---- x_proj MFMA: (32x256)@(256x48) -> sdt16(bf16) | sB+Bv | Cv
    {
        const int mh = (w & 1) * 16;
        const int nh = (w >> 1) * 32;
        f32x4 acc0 = {0.f,0.f,0.f,0.f}, acc1 = {0.f,0.f,0.f,0.f};
        #pragma unroll
        for (int k0 = 0; k0 < 256; k0 += 32) {
            const bf16x8 a  = *(const bf16x8*)&As[mh + cl][k0 + rq*8];
            const bf16x8 b0 = *(const bf16x8*)&Wxt[(size_t)(nh + cl)*DD + k0 + rq*8];
            acc0 = __builtin_amdgcn_mfma_f32_16x16x32_bf16(a, b0, acc0, 0, 0, 0);
            if (w < 2) {
                const bf16x8 b1 = *(const bf16x8*)&Wxt[(size_t)(nh + 16 + cl)*DD + k0 + rq*8];
                acc1 = __builtin_amdgcn_mfma_f32_16x16x32_bf16(a, b1, acc1, 0, 0, 0);
            }
        }
        if (w < 2) {
            #pragma unroll
            for (int r = 0; r < 4; ++r) {
                const int rr = mh + rq*4 + r;
                sdt16[rr][cl] = f2bf(acc0[r]);
                sB[rr][cl]    = acc1[r];
                Bv[(m0 + rr)*NN + cl] = acc1[r];
            }
        } else {
            #pragma unroll
            for (int r = 0; r < 4; ++r)
                Cv[(m0 + mh + rq*4 + r)*NN + cl] = acc0[r];
        }
    }
    __syncthreads();

    // ---- dt_proj MFMA: (32x32K)@(32Kx256) -> softplus -> sDel + global delta
    {
        const int mh = (w & 1) * 16;
        const int nbase = (w >> 1) * 8;          // 8 n-tiles per wave
        const bf16x8 a = *(const bf16x8*)&sdt16[mh + cl][rq*8];
        #pragma unroll
        for (int nt = 0; nt < 8; ++nt) {
            const int n0 = (nbase + nt) * 16;
            const bf16x8 b = *(const bf16x8*)&Dwt[(size_t)(n0 + cl)*32 + rq*8];
            f32x4 acc = {0.f,0.f,0.f,0.f};
            acc = __builtin_amdgcn_mfma_f32_16x16x32_bf16(a, b, acc, 0, 0, 0);
            const float bia = sdtb[n0 + cl];
            #pragma unroll
            for (int r = 0; r < 4; ++r) {
                const float ac = acc[r] + bia;
                const float sp = (ac > 15.f) ? ac
                    : 0.69314718f * log2f(1.f + exp2f(ac * 1.44269504f));
                const unsigned short db = f2bf(sp);
                const int rr = mh + rq*4 + r;
                sDel[rr][n0 + cl] = db;
                delta[(m0 + rr)*DD + n0 + cl] = db;
            }
        }
    }
    __syncthreads();

    // ---- scan pass 1 (thread t = column d)
    float h[NN];
    #pragma unroll
    for (int n = 0; n < NN; ++n) h[n] = 0.f;
    float dsum = 0.f;
    if (fast) scan1_loop<true >(sDel, As, sB, al, t, h, &dsum);
    else      scan1_loop<false>(sDel, As, sB, al, t, h, &dsum);
    const size_t o = (size_t)blk * NN * DD + t;
    #pragma unroll
    for (int n = 0; n < NN; ++n) S[o + n*DD] = f2bf(h[n]);
    Dsum[(size_t)blk*DD + t] = dsum;
}

// ---------------------------------------------------------------------------
// combine: fold over 64 chunks -> Hin (bf16 in/out, fp32 accumulate)
// ---------------------------------------------------------------------------
__global__ __launch_bounds__(256) void k_combine(
    const unsigned short* __restrict__ S, const float* __restrict__ Dsum,
    const float* __restrict__ A_log, unsigned short* __restrict__ Hin)
{
    const int bi = blockIdx.x;
    const int d = threadIdx.x;
    const int n = bi & 15;
    const int b = bi >> 4;
    const float al = -expf(A_log[d*NN + n]) * 1.44269504f;
    float h = 0.f;
    for (int c0 = 0; c0 < CH; c0 += 8) {
        float ds8[8];
        unsigned short s8[8];
        #pragma unroll
        for (int i = 0; i < 8; ++i) {
            const size_t blk = (size_t)b*CH + c0 + i;
            ds8[i] = Dsum[blk*DD + d];
            s8[i]  = S[(blk*NN + n)*DD + d];
        }
        #pragma unroll
        for (int i = 0; i < 8; ++i) {
            const size_t blk = (size_t)b*CH + c0 + i;
            Hin[(blk*NN + n)*DD + d] = f2bf(h);
            h = fmaf(exp2f(al * ds8[i]), h, bf2f(s8[i]));
        }
    }
}

// ---------------------------------------------------------------------------
// scan pass 2 — LDS-staged, float4 B/C reads, produces g = gelu(y) (over delta)
// ---------------------------------------------------------------------------
template<bool FAST>
__device__ __forceinline__ void scan2_loop(
    const unsigned short (*sD)[264], const unsigned short (*sX)[264],
    const float (*sB)[20], const float (*sC)[20],
    const float* al, int d, float* h, float dsk,
    size_t gout, unsigned short* __restrict__ g)
{
    #pragma unroll 4
    for (int l = 0; l < LC; ++l) {
        const float dl = bf2f(sD[l][d]);
        const float xl = bf2f(sX[l][d]);
        const float dx = dl * xl;
        float e[NN];
        if (FAST) pow_tree(exp2f(al[0]*dl), e);
        else {
            #pragma unroll
            for (int n = 0; n < NN; ++n) e[n] = exp2f(al[n]*dl);
        }
        const float4 B0 = *(const float4*)&sB[l][0];
        const float4 B1 = *(const float4*)&sB[l][4];
        const float4 B2 = *(const float4*)&sB[l][8];
        const float4 B3 = *(const float4*)&sB[l][12];
        const float bb[16] = {B0.x,B0.y,B0.z,B0.w, B1.x,B1.y,B1.z,B1.w,
                              B2.x,B2.y,B2.z,B2.w, B3.x,B3.y,B3.z,B3.w};
        const float4 C0 = *(const float4*)&sC[l][0];
        const float4 C1 = *(const float4*)&sC[l][4];
        const float4 C2 = *(const float4*)&sC[l][8];
        const float4 C3 = *(const float4*)&sC[l][12];
        const float cc[16] = {C0.x,C0.y,C0.z,C0.w, C1.x,C1.y,C1.z,C1.w,
                              C2.x,C2.y,C2.z,C2.w, C3.x,C3.y,C3.z,C3.w};
        float yb[4] = {0.f, 0.f, 0.f, 0.f};
        #pragma unroll
        for (int n = 0; n < NN; ++n) {
            h[n] = fmaf(e[n], h[n], dx * bb[n]);
            yb[n & 3] = fmaf(h[n], cc[n], yb[n & 3]);
        }
        const float vv = (yb[0]+yb[1]) + (yb[2]+yb[3]) + xl * dsk;
        const float u  = 0.7978845608f * (vv + 0.044715f*vv*vv*vv);
        const float t2 = exp2f(2.8853900818f * u);
        const float th = 1.f - 2.f/(t2 + 1.f);
        g[gout + (size_t)l*DD] = f2bf(0.5f * vv * (1.f + th));
    }
}

__global__ __launch_bounds__(256) void k_scan2(
    const unsigned short* __restrict__ delta,
    const unsigned short* __restrict__ xln,
    const float* __restrict__ Bv,
    const float* __restrict__ Cv,
    const float* __restrict__ A_log,
    const unsigned short* __restrict__ Hin,   // bf16
    const float* __restrict__ Dskip,
    unsigned short* __restrict__ g)
{
    const int blk = blockIdx.x;
    const int c = blk & (CH-1);
    const int b = blk >> 6;
    const int d = threadIdx.x;
    const int l0 = c * LC;
    __shared__ unsigned short sD[LC][264];
    __shared__ unsigned short sX[LC][264];
    __shared__ float sB[LC][20], sC[LC][20];
    {
        const int sr = d >> 3, sc = (d & 7) * 32;
        const size_t gbase = ((size_t)b*LL + l0 + sr)*DD + sc;
        #pragma unroll
        for (int i = 0; i < 4; ++i) {
            *(bf16x8*)&sD[sr][sc + i*8] = *(const bf16x8*)&delta[gbase + i*8];
            *(bf16x8*)&sX[sr][sc + i*8] = *(const bf16x8*)&xln  [gbase + i*8];
        }
        if (d < 128) {
            const int l = d >> 2, qq = (d & 3) * 4;
            *(float4*)&sB[l][qq] = *(const float4*)&Bv[((size_t)b*LL + l0 + l)*NN + qq];
        } else {
            const int dd = d - 128;
            const int l = dd >> 2, qq = (dd & 3) * 4;
            *(float4*)&sC[l][qq] = *(const float4*)&Cv[((size_t)b*LL + l0 + l)*NN + qq];
        }
    }
    float al[NN];
    bool fast = true;
    #pragma unroll
    for (int n = 0; n < NN; ++n) {
        al[n] = -expf(A_log[d*NN + n]) * 1.44269504f;
        fast = fast && (fabsf(al[n] - (n+1)*al[0]) <= 1e-3f*fabsf(al[n]) + 1e-6f);
    }
    float h[NN];
    const size_t ob = (size_t)blk * NN * DD + d;
    #pragma unroll
    for (int n = 0; n < NN; ++n) h[n] = bf2f(Hin[ob + n*DD]);
    const float dsk = Dskip[d];
    __syncthreads();
    const size_t gout = ((size_t)b*LL + l0)*DD + d;
    if (fast) scan2_loop<true >(sD, sX, sB, sC, al, d, h, dsk, gout, g);
    else      scan2_loop<false>(sD, sX, sB, sC, al, d, h, dsk, gout, g);
}

// ---------------------------------------------------------------------------
// GLU GEMM (32768x256 @ 256x512) + bias + sigmoid gate + skip
// ---------------------------------------------------------------------------
__global__ __launch_bounds__(256) void k_glu(
    const unsigned short* __restrict__ g,
    const unsigned short* __restrict__ Wt,
    const float* __restrict__ gb,
    const float* __restrict__ x,
    float* __restrict__ out)
{
    __shared__ unsigned short As[64][40];
    __shared__ unsigned short Bl[64][40];
    __shared__ unsigned short Bh[64][40];
    const int n0 = blockIdx.x * 64;
    const int m0 = blockIdx.y * 64;
    const int t = threadIdx.x;
    const int w = t >> 6, lane = t & 63;
    const int r = t >> 2, q = t & 3;
    const int cl = lane & 15, rq = lane >> 4;
    f32x4 accL[4], accH[4];
    const f32x4 zz = {0.f, 0.f, 0.f, 0.f};
    #pragma unroll
    for (int nf = 0; nf < 4; ++nf) { accL[nf] = zz; accH[nf] = zz; }

    for (int k0 = 0; k0 < 256; k0 += 32) {
        *(bf16x8*)(&As[r][q*8]) = *(const bf16x8*)(&g [(size_t)(m0+r)*DD + k0 + q*8]);
        *(bf16x8*)(&Bl[r][q*8]) = *(const bf16x8*)(&Wt[(size_t)(n0+r)*DD + k0 + q*8]);
        *(bf16x8*)(&Bh[r][q*8]) = *(const bf16x8*)(&Wt[(size_t)(n0+256+r)*DD + k0 + q*8]);
        __syncthreads();
        const bf16x8 a = *(const bf16x8*)(&As[w*16 + cl][rq*8]);
        #pragma unroll
        for (int nf = 0; nf < 4; ++nf) {
            const bf16x8 bl = *(const bf16x8*)(&Bl[nf*16 + cl][rq*8]);
            const bf16x8 bh = *(const bf16x8*)(&Bh[nf*16 + cl][rq*8]);
            accL[nf] = __builtin_amdgcn_mfma_f32_16x16x32_bf16(a, bl, accL[nf], 0, 0, 0);
            accH[nf] = __builtin_amdgcn_mfma_f32_16x16x32_bf16(a, bh, accH[nf], 0, 0, 0);
        }
        __syncthreads();
    }
    #pragma unroll
    for (int nf = 0; nf < 4; ++nf) {
        const int j = n0 + nf*16 + cl;
        const float bL = gb[j];
        const float bH = gb[j + 256];
        #pragma unroll
        for (int rr = 0; rr < 4; ++rr) {
            const int m = m0 + w*16 + rq*4 + rr;
            const float lo = accL[nf][rr] + bL;
            const float hi = accH[nf][rr] + bH;
            const float sg = 1.f / (1.f + exp2f(-1.44269504f * hi));
            out[(size_t)m*DD + j] = lo * sg + x[(size_t)m*DD + j];
        }
    }
}

extern "C" void kernel_launch(void* const* d_in, const int* in_sizes, int n_in,
                              void* d_out, int out_size, void* d_ws, size_t ws_size,
                              hipStream_t stream)
{
    const float* x    = (const float*)d_in[0];
    const float* ln_w = (const float*)d_in[1];
    const float* ln_b = (const float*)d_in[2];
    const float* xpw  = (const float*)d_in[3];
    const float* dtw  = (const float*)d_in[4];
    const float* dtb  = (const float*)d_in[5];
    const float* alog = (const float*)d_in[6];
    const float* dsk  = (const float*)d_in[7];
    const float* gw   = (const float*)d_in[8];
    const float* gb   = (const float*)d_in[9];
    float* out = (float*)d_out;

    char* ws = (char*)d_ws;
    size_t off = 0;
    auto alloc = [&](size_t bytes) {
        char* p = ws + off; off += (bytes + 255) & ~(size_t)255; return p;
    };
    unsigned short* xln    = (unsigned short*)alloc((size_t)BB*LL*DD*2);
    unsigned short* deltaG = (unsigned short*)alloc((size_t)BB*LL*DD*2);
    float*          Bvp    = (float*)         alloc((size_t)BB*LL*NN*4);
    float*          Cvp    = (float*)         alloc((size_t)BB*LL*NN*4);
    unsigned short* S      = (unsigned short*)alloc((size_t)BB*CH*NN*DD*2);
    float*          Dsum   = (float*)         alloc((size_t)BB*CH*DD*4);
    unsigned short* Hin    = (unsigned short*)alloc((size_t)BB*CH*NN*DD*2);
    unsigned short* Wt     = (unsigned short*)alloc((size_t)512*256*2);
    unsigned short* Wxt    = (unsigned short*)alloc((size_t)64*256*2);
    unsigned short* Dwt    = (unsigned short*)alloc((size_t)256*32*2);
    unsigned short* g      = deltaG;   // scan2 overwrites delta (staged first)

    k_prep<<<145, 256, 0, stream>>>(xpw, gw, dtw, Wxt, Wt, Dwt);
    k_ln_scan1<<<BB*CH, 256, 0, stream>>>(x, ln_w, ln_b, Wxt, Dwt, dtb, alog,
                                          xln, deltaG, Bvp, Cvp, S, Dsum);
    k_combine<<<256, 256, 0, stream>>>(S, Dsum, alog, Hin);
    k_scan2<<<BB*CH, 256, 0, stream>>>(deltaG, xln, Bvp, Cvp, alog, Hin, dsk, g);
    k_glu<<<dim3(4, 512), 256, 0, stream>>>(g, Wt, gb, x, out);
}

// Round 16
// 107.366 us; speedup vs baseline: 2.4397x; 1.0329x over previous
//
#include <hip/hip_runtime.h>
#include <hip/hip_bf16.h>

#define BB 16
#define LL 2048
#define DD 256
#define NN 16
#define RR 16
#define CH 64
#define LC (LL/CH)   /* 32 */

static __device__ __forceinline__ float bf2f(unsigned short u) {
    return __uint_as_float(((unsigned)u) << 16);
}
static __device__ __forceinline__ unsigned short f2bf(float f) {
    unsigned u = __float_as_uint(f);
    u += 0x7FFFu + ((u >> 16) & 1u);
    return (unsigned short)(u >> 16);
}

typedef __attribute__((ext_vector_type(8))) short bf16x8;
typedef __attribute__((ext_vector_type(4))) short bf16x4;
typedef __attribute__((ext_vector_type(4))) float f32x4;

// al[n] = -exp(A_log)*log2(e), computed via exp2 (identical in all kernels)
static __device__ __forceinline__ float neg_exp_log2e(float a) {
    return -exp2f(a * 1.44269504f) * 1.44269504f;
}

// e[n] = E^(n+1), depth-4 product tree
static __device__ __forceinline__ void pow_tree(float E, float* e) {
    e[0] = E;
    e[1] = E * E;
    e[2] = e[1] * E;
    e[3] = e[1] * e[1];
    e[4] = e[3] * e[0];  e[5] = e[3] * e[1];  e[6] = e[3] * e[2];  e[7] = e[3] * e[3];
    e[8] = e[7] * e[0];  e[9] = e[7] * e[1];  e[10] = e[7] * e[2]; e[11] = e[7] * e[3];
    e[12] = e[7] * e[4]; e[13] = e[7] * e[5]; e[14] = e[7] * e[6]; e[15] = e[7] * e[7];
}

// ---------------------------------------------------------------------------
// prep: bid<16 -> Wxt (xw^T bf16, 48->64 pad); bid 16..143 -> Wt (glu_w^T);
// bid 144 -> Dwt (dtw^T, 256x32 bf16, K zero-padded 16->32)
// ---------------------------------------------------------------------------
__global__ __launch_bounds__(256) void k_prep(
    const float* __restrict__ xw, const float* __restrict__ gw,
    const float* __restrict__ dtw,
    unsigned short* __restrict__ Wxt, unsigned short* __restrict__ Wt,
    unsigned short* __restrict__ Dwt)
{
    __shared__ unsigned short s[32][33];
    const int bid = blockIdx.x;
    const int t = threadIdx.x;
    if (bid < 16) {
        const int idx = bid * 256 + t;
        const int n  = idx >> 6;
        const int k0 = (idx & 63) * 4;
        #pragma unroll
        for (int i = 0; i < 4; ++i) {
            float v = (n < 48) ? xw[(size_t)(k0 + i) * 48 + n] : 0.f;
            Wxt[(size_t)n * DD + k0 + i] = f2bf(v);
        }
    } else if (bid < 144) {
        const int bb = bid - 16;
        const int bx = bb & 15, by = bb >> 4;
        const int r = t >> 5, cc = t & 31;
        #pragma unroll
        for (int i = 0; i < 4; ++i)
            s[r + 8*i][cc] = f2bf(gw[(size_t)(by*32 + r + 8*i)*512 + bx*32 + cc]);
        __syncthreads();
        #pragma unroll
        for (int i = 0; i < 4; ++i)
            Wt[(size_t)(bx*32 + r + 8*i)*256 + by*32 + cc] = s[cc][r + 8*i];
    } else {
        unsigned short r32[32];
        #pragma unroll
        for (int k = 0; k < 16; ++k) r32[k] = f2bf(dtw[(size_t)k*DD + t]);
        #pragma unroll
        for (int k = 16; k < 32; ++k) r32[k] = 0;
        #pragma unroll
        for (int i = 0; i < 4; ++i)
            *(bf16x8*)&Dwt[(size_t)t*32 + i*8] = *(bf16x8*)&r32[i*8];
    }
}

// ---------------------------------------------------------------------------
// k_ln_scan1: LN -> x_proj MFMA -> dt_proj MFMA + softplus -> scan pass 1.
// LDS = 40960 B exactly -> 4 blocks/CU (single dispatch round, no tail).
// ---------------------------------------------------------------------------
template<bool FAST>
__device__ __forceinline__ void scan1_loop(
    const unsigned short (*sDel)[264], const unsigned short (*As)[264],
    const float (*sB)[20], const float* al, int t,
    float* h, float* dsum)
{
    #pragma unroll 4
    for (int l = 0; l < LC; ++l) {
        const float dl = bf2f(sDel[l][t]);
        const float xl = bf2f(As[l][t]);
        const float dx = dl * xl;
        *dsum += dl;
        float e[NN];
        if (FAST) pow_tree(exp2f(al[0]*dl), e);
        else {
            #pragma unroll
            for (int n = 0; n < NN; ++n) e[n] = exp2f(al[n]*dl);
        }
        const float4 B0 = *(const float4*)&sB[l][0];
        const float4 B1 = *(const float4*)&sB[l][4];
        const float4 B2 = *(const float4*)&sB[l][8];
        const float4 B3 = *(const float4*)&sB[l][12];
        const float bb[16] = {B0.x,B0.y,B0.z,B0.w, B1.x,B1.y,B1.z,B1.w,
                              B2.x,B2.y,B2.z,B2.w, B3.x,B3.y,B3.z,B3.w};
        #pragma unroll
        for (int n = 0; n < NN; ++n)
            h[n] = fmaf(e[n], h[n], dx * bb[n]);
    }
}

__global__ __launch_bounds__(256) void k_ln_scan1(
    const float* __restrict__ x,
    const float* __restrict__ ln_w,
    const float* __restrict__ ln_b,
    const unsigned short* __restrict__ Wxt,
    const unsigned short* __restrict__ Dwt,
    const float* __restrict__ dtb,
    const float* __restrict__ A_log,
    unsigned short* __restrict__ xln,
    unsigned short* __restrict__ delta,
    float* __restrict__ Bv,
    float* __restrict__ Cv,
    unsigned short* __restrict__ S,     // bf16
    float* __restrict__ Dsum)
{
    const int t = threadIdx.x;
    const int blk = blockIdx.x;
    const size_t m0 = (size_t)blk * LC;
    const int row = t >> 3, seg = t & 7;
    const size_t grow = m0 + row;

    __shared__ unsigned short As[LC][264];     // 16896 B
    __shared__ unsigned short sDel[LC][264];   // 16896 B
    __shared__ unsigned short sdt16[LC][40];   // 2560 B
    __shared__ float sB[LC][20];               // 2560 B
    __shared__ float slnw[256], slnb[256];     // 2048 B  (total 40960)

    // ---- stage ln_w/ln_b + zero-fill sdt16 K-pad columns
    {
        const int tt = t & 63;
        if (t < 64)       *(float4*)&slnw[tt*4] = *(const float4*)&ln_w[tt*4];
        else if (t < 128) *(float4*)&slnb[tt*4] = *(const float4*)&ln_b[tt*4];
        if (t < 64) {
            const bf16x8 z = {0,0,0,0,0,0,0,0};
            *(bf16x8*)&sdt16[t >> 1][16 + (t & 1)*8] = z;
        }
    }
    float al[NN];
    bool fast = true;
    #pragma unroll
    for (int n = 0; n < NN; ++n) {
        al[n] = neg_exp_log2e(A_log[t*NN + n]);
        fast = fast && (fabsf(al[n] - (n+1)*al[0]) <= 1e-3f*fabsf(al[n]) + 1e-6f);
    }

    // ---- LN (8 threads/row, 32 floats/thread, strided)
    float v[32];
    #pragma unroll
    for (int i = 0; i < 8; ++i)
        *(float4*)&v[i*4] = *(const float4*)(x + grow*DD + i*32 + seg*4);
    float s = 0.f, q = 0.f;
    #pragma unroll
    for (int i = 0; i < 32; ++i) { s += v[i]; q = fmaf(v[i], v[i], q); }
    #pragma unroll
    for (int o = 1; o < 8; o <<= 1) {
        s += __shfl_xor(s, o);
        q += __shfl_xor(q, o);
    }
    const float mu = s * (1.f/DD);
    const float rs = rsqrtf(q * (1.f/DD) - mu*mu + 1e-5f);
    __syncthreads();
    #pragma unroll
    for (int i = 0; i < 8; ++i) {
        const int c = i*32 + seg*4;
        const float4 wv = *(const float4*)&slnw[c];
        const float4 bv = *(const float4*)&slnb[c];
        unsigned short o16[4];
        o16[0] = f2bf((v[i*4+0]-mu)*rs*wv.x + bv.x);
        o16[1] = f2bf((v[i*4+1]-mu)*rs*wv.y + bv.y);
        o16[2] = f2bf((v[i*4+2]-mu)*rs*wv.z + bv.z);
        o16[3] = f2bf((v[i*4+3]-mu)*rs*wv.w + bv.w);
        *(bf16x4*)&xln[grow*DD + c] = *(bf16x4*)&o16[0];
        *(bf16x4*)&As[row][c]       = *(bf16x4*)&o16[0];
    }
    __syncthreads();

    const int w = t >> 6, lane = t & 63;
    const int cl = lane & 15, rq = lane >> 4;

    // ---- x_proj MFMA: (32x256)@(256x48) -> sdt16(bf16) | sB+Bv | Cv
    {
        const int mh = (w & 1) * 16;
        const int nh = (w >> 1) * 32;
        f32x4 acc0 = {0.f,0.f,0.f,0.f}, acc1 = {0.f,0.f,0.f,0.f};
        #pragma unroll
        for (int k0 = 0; k0 < 256; k0 += 32) {
            const bf16x8 a  = *(const bf16x8*)&As[mh + cl][k0 + rq*8];
            const bf16x8 b0 = *(const bf16x8*)&Wxt[(size_t)(nh + cl)*DD + k0 + rq*8];
            acc0 = __builtin_amdgcn_mfma_f32_16x16x32_bf16(a, b0, acc0, 0, 0, 0);
            if (w < 2) {
                const bf16x8 b1 = *(const bf16x8*)&Wxt[(size_t)(nh + 16 + cl)*DD + k0 + rq*8];
                acc1 = __builtin_amdgcn_mfma_f32_16x16x32_bf16(a, b1, acc1, 0, 0, 0);
            }
        }
        if (w < 2) {
            #pragma unroll
            for (int r = 0; r < 4; ++r) {
                const int rr = mh + rq*4 + r;
                sdt16[rr][cl] = f2bf(acc0[r]);
                sB[rr][cl]    = acc1[r];
                Bv[(m0 + rr)*NN + cl] = acc1[r];
            }
        } else {
            #pragma unroll
            for (int r = 0; r < 4; ++r)
                Cv[(m0 + mh + rq*4 + r)*NN + cl] = acc0[r];
        }
    }
    __syncthreads();

    // ---- dt_proj MFMA: (32x32K)@(32Kx256) -> softplus -> sDel + global delta
    // dtb read direct from global (L1 broadcast; was LDS-staged, freed 1KB)
    {
        const int mh = (w & 1) * 16;
        const int nbase = (w >> 1) * 8;
        const bf16x8 a = *(const bf16x8*)&sdt16[mh + cl][rq*8];
        #pragma unroll
        for (int nt = 0; nt < 8; ++nt) {
            const int n0 = (nbase + nt) * 16;
            const bf16x8 b = *(const bf16x8*)&Dwt[(size_t)(n0 + cl)*32 + rq*8];
            f32x4 acc = {0.f,0.f,0.f,0.f};
            acc = __builtin_amdgcn_mfma_f32_16x16x32_bf16(a, b, acc, 0, 0, 0);
            const float bia = dtb[n0 + cl];
            #pragma unroll
            for (int r = 0; r < 4; ++r) {
                const float ac = acc[r] + bia;
                const float sp = (ac > 15.f) ? ac
                    : 0.69314718f * log2f(1.f + exp2f(ac * 1.44269504f));
                const unsigned short db = f2bf(sp);
                const int rr = mh + rq*4 + r;
                sDel[rr][n0 + cl] = db;
                delta[(m0 + rr)*DD + n0 + cl] = db;
            }
        }
    }
    __syncthreads();

    // ---- scan pass 1 (thread t = column d)
    float h[NN];
    #pragma unroll
    for (int n = 0; n < NN; ++n) h[n] = 0.f;
    float dsum = 0.f;
    if (fast) scan1_loop<true >(sDel, As, sB, al, t, h, &dsum);
    else      scan1_loop<false>(sDel, As, sB, al, t, h, &dsum);
    const size_t o = (size_t)blk * NN * DD + t;
    #pragma unroll
    for (int n = 0; n < NN; ++n) S[o + n*DD] = f2bf(h[n]);
    Dsum[(size_t)blk*DD + t] = dsum;
}

// ---------------------------------------------------------------------------
// combine: fold over 64 chunks -> Hin (bf16 in/out, fp32 accumulate)
// ---------------------------------------------------------------------------
__global__ __launch_bounds__(256) void k_combine(
    const unsigned short* __restrict__ S, const float* __restrict__ Dsum,
    const float* __restrict__ A_log, unsigned short* __restrict__ Hin)
{
    const int bi = blockIdx.x;
    const int d = threadIdx.x;
    const int n = bi & 15;
    const int b = bi >> 4;
    const float al = neg_exp_log2e(A_log[d*NN + n]);
    float h = 0.f;
    for (int c0 = 0; c0 < CH; c0 += 8) {
        float ds8[8];
        unsigned short s8[8];
        #pragma unroll
        for (int i = 0; i < 8; ++i) {
            const size_t blk = (size_t)b*CH + c0 + i;
            ds8[i] = Dsum[blk*DD + d];
            s8[i]  = S[(blk*NN + n)*DD + d];
        }
        #pragma unroll
        for (int i = 0; i < 8; ++i) {
            const size_t blk = (size_t)b*CH + c0 + i;
            Hin[(blk*NN + n)*DD + d] = f2bf(h);
            h = fmaf(exp2f(al * ds8[i]), h, bf2f(s8[i]));
        }
    }
}

// ---------------------------------------------------------------------------
// scan pass 2 — LDS-staged, float4 B/C reads, produces g = gelu(y) (over delta)
// ---------------------------------------------------------------------------
template<bool FAST>
__device__ __forceinline__ void scan2_loop(
    const unsigned short (*sD)[264], const unsigned short (*sX)[264],
    const float (*sB)[20], const float (*sC)[20],
    const float* al, int d, float* h, float dsk,
    size_t gout, unsigned short* __restrict__ g)
{
    #pragma unroll 4
    for (int l = 0; l < LC; ++l) {
        const float dl = bf2f(sD[l][d]);
        const float xl = bf2f(sX[l][d]);
        const float dx = dl * xl;
        float e[NN];
        if (FAST) pow_tree(exp2f(al[0]*dl), e);
        else {
            #pragma unroll
            for (int n = 0; n < NN; ++n) e[n] = exp2f(al[n]*dl);
        }
        const float4 B0 = *(const float4*)&sB[l][0];
        const float4 B1 = *(const float4*)&sB[l][4];
        const float4 B2 = *(const float4*)&sB[l][8];
        const float4 B3 = *(const float4*)&sB[l][12];
        const float bb[16] = {B0.x,B0.y,B0.z,B0.w, B1.x,B1.y,B1.z,B1.w,
                              B2.x,B2.y,B2.z,B2.w, B3.x,B3.y,B3.z,B3.w};
        const float4 C0 = *(const float4*)&sC[l][0];
        const float4 C1 = *(const float4*)&sC[l][4];
        const float4 C2 = *(const float4*)&sC[l][8];
        const float4 C3 = *(const float4*)&sC[l][12];
        const float cc[16] = {C0.x,C0.y,C0.z,C0.w, C1.x,C1.y,C1.z,C1.w,
                              C2.x,C2.y,C2.z,C2.w, C3.x,C3.y,C3.z,C3.w};
        float yb[4] = {0.f, 0.f, 0.f, 0.f};
        #pragma unroll
        for (int n = 0; n < NN; ++n) {
            h[n] = fmaf(e[n], h[n], dx * bb[n]);
            yb[n & 3] = fmaf(h[n], cc[n], yb[n & 3]);
        }
        const float vv = (yb[0]+yb[1]) + (yb[2]+yb[3]) + xl * dsk;
        const float u  = 0.7978845608f * (vv + 0.044715f*vv*vv*vv);
        const float t2 = exp2f(2.8853900818f * u);
        const float th = 1.f - 2.f/(t2 + 1.f);
        g[gout + (size_t)l*DD] = f2bf(0.5f * vv * (1.f + th));
    }
}

__global__ __launch_bounds__(256) void k_scan2(
    const unsigned short* __restrict__ delta,
    const unsigned short* __restrict__ xln,
    const float* __restrict__ Bv,
    const float* __restrict__ Cv,
    const float* __restrict__ A_log,
    const unsigned short* __restrict__ Hin,   // bf16
    const float* __restrict__ Dskip,
    unsigned short* __restrict__ g)
{
    const int blk = blockIdx.x;
    const int c = blk & (CH-1);
    const int b = blk >> 6;
    const int d = threadIdx.x;
    const int l0 = c * LC;
    __shared__ unsigned short sD[LC][264];
    __shared__ unsigned short sX[LC][264];
    __shared__ float sB[LC][20], sC[LC][20];
    {
        const int sr = d >> 3, sc = (d & 7) * 32;
        const size_t gbase = ((size_t)b*LL + l0 + sr)*DD + sc;
        #pragma unroll
        for (int i = 0; i < 4; ++i) {
            *(bf16x8*)&sD[sr][sc + i*8] = *(const bf16x8*)&delta[gbase + i*8];
            *(bf16x8*)&sX[sr][sc + i*8] = *(const bf16x8*)&xln  [gbase + i*8];
        }
        if (d < 128) {
            const int l = d >> 2, qq = (d & 3) * 4;
            *(float4*)&sB[l][qq] = *(const float4*)&Bv[((size_t)b*LL + l0 + l)*NN + qq];
        } else {
            const int dd = d - 128;
            const int l = dd >> 2, qq = (dd & 3) * 4;
            *(float4*)&sC[l][qq] = *(const float4*)&Cv[((size_t)b*LL + l0 + l)*NN + qq];
        }
    }
    float al[NN];
    bool fast = true;
    #pragma unroll
    for (int n = 0; n < NN; ++n) {
        al[n] = neg_exp_log2e(A_log[d*NN + n]);
        fast = fast && (fabsf(al[n] - (n+1)*al[0]) <= 1e-3f*fabsf(al[n]) + 1e-6f);
    }
    float h[NN];
    const size_t ob = (size_t)blk * NN * DD + d;
    #pragma unroll
    for (int n = 0; n < NN; ++n) h[n] = bf2f(Hin[ob + n*DD]);
    const float dsk = Dskip[d];
    __syncthreads();
    const size_t gout = ((size_t)b*LL + l0)*DD + d;
    if (fast) scan2_loop<true >(sD, sX, sB, sC, al, d, h, dsk, gout, g);
    else      scan2_loop<false>(sD, sX, sB, sC, al, d, h, dsk, gout, g);
}

// ---------------------------------------------------------------------------
// GLU GEMM (32768x256 @ 256x512) + bias + sigmoid gate + skip
// ---------------------------------------------------------------------------
__global__ __launch_bounds__(256) void k_glu(
    const unsigned short* __restrict__ g,
    const unsigned short* __restrict__ Wt,
    const float* __restrict__ gb,
    const float* __restrict__ x,
    float* __restrict__ out)
{
    __shared__ unsigned short As[64][40];
    __shared__ unsigned short Bl[64][40];
    __shared__ unsigned short Bh[64][40];
    const int n0 = blockIdx.x * 64;
    const int m0 = blockIdx.y * 64;
    const int t = threadIdx.x;
    const int w = t >> 6, lane = t & 63;
    const int r = t >> 2, q = t & 3;
    const int cl = lane & 15, rq = lane >> 4;
    f32x4 accL[4], accH[4];
    const f32x4 zz = {0.f, 0.f, 0.f, 0.f};
    #pragma unroll
    for (int nf = 0; nf < 4; ++nf) { accL[nf] = zz; accH[nf] = zz; }

    for (int k0 = 0; k0 < 256; k0 += 32) {
        *(bf16x8*)(&As[r][q*8]) = *(const bf16x8*)(&g [(size_t)(m0+r)*DD + k0 + q*8]);
        *(bf16x8*)(&Bl[r][q*8]) = *(const bf16x8*)(&Wt[(size_t)(n0+r)*DD + k0 + q*8]);
        *(bf16x8*)(&Bh[r][q*8]) = *(const bf16x8*)(&Wt[(size_t)(n0+256+r)*DD + k0 + q*8]);
        __syncthreads();
        const bf16x8 a = *(const bf16x8*)(&As[w*16 + cl][rq*8]);
        #pragma unroll
        for (int nf = 0; nf < 4; ++nf) {
            const bf16x8 bl = *(const bf16x8*)(&Bl[nf*16 + cl][rq*8]);
            const bf16x8 bh = *(const bf16x8*)(&Bh[nf*16 + cl][rq*8]);
            accL[nf] = __builtin_amdgcn_mfma_f32_16x16x32_bf16(a, bl, accL[nf], 0, 0, 0);
            accH[nf] = __builtin_amdgcn_mfma_f32_16x16x32_bf16(a, bh, accH[nf], 0, 0, 0);
        }
        __syncthreads();
    }
    #pragma unroll
    for (int nf = 0; nf < 4; ++nf) {
        const int j = n0 + nf*16 + cl;
        const float bL = gb[j];
        const float bH = gb[j + 256];
        #pragma unroll
        for (int rr = 0; rr < 4; ++rr) {
            const int m = m0 + w*16 + rq*4 + rr;
            const float lo = accL[nf][rr] + bL;
            const float hi = accH[nf][rr] + bH;
            const float sg = 1.f / (1.f + exp2f(-1.44269504f * hi));
            out[(size_t)m*DD + j] = lo * sg + x[(size_t)m*DD + j];
        }
    }
}

extern "C" void kernel_launch(void* const* d_in, const int* in_sizes, int n_in,
                              void* d_out, int out_size, void* d_ws, size_t ws_size,
                              hipStream_t stream)
{
    const float* x    = (const float*)d_in[0];
    const float* ln_w = (const float*)d_in[1];
    const float* ln_b = (const float*)d_in[2];
    const float* xpw  = (const float*)d_in[3];
    const float* dtw  = (const float*)d_in[4];
    const float* dtb  = (const float*)d_in[5];
    const float* alog = (const float*)d_in[6];
    const float* dsk  = (const float*)d_in[7];
    const float* gw   = (const float*)d_in[8];
    const float* gb   = (const float*)d_in[9];
    float* out = (float*)d_out;

    char* ws = (char*)d_ws;
    size_t off = 0;
    auto alloc = [&](size_t bytes) {
        char* p = ws + off; off += (bytes + 255) & ~(size_t)255; return p;
    };
    unsigned short* xln    = (unsigned short*)alloc((size_t)BB*LL*DD*2);
    unsigned short* deltaG = (unsigned short*)alloc((size_t)BB*LL*DD*2);
    float*          Bvp    = (float*)         alloc((size_t)BB*LL*NN*4);
    float*          Cvp    = (float*)         alloc((size_t)BB*LL*NN*4);
    unsigned short* S      = (unsigned short*)alloc((size_t)BB*CH*NN*DD*2);
    float*          Dsum   = (float*)         alloc((size_t)BB*CH*DD*4);
    unsigned short* Hin    = (unsigned short*)alloc((size_t)BB*CH*NN*DD*2);
    unsigned short* Wt     = (unsigned short*)alloc((size_t)512*256*2);
    unsigned short* Wxt    = (unsigned short*)alloc((size_t)64*256*2);
    unsigned short* Dwt    = (unsigned short*)alloc((size_t)256*32*2);
    unsigned short* g      = deltaG;   // scan2 overwrites delta (staged first)

    k_prep<<<145, 256, 0, stream>>>(xpw, gw, dtw, Wxt, Wt, Dwt);
    k_ln_scan1<<<BB*CH, 256, 0, stream>>>(x, ln_w, ln_b, Wxt, Dwt, dtb, alog,
                                          xln, deltaG, Bvp, Cvp, S, Dsum);
    k_combine<<<256, 256, 0, stream>>>(S, Dsum, alog, Hin);
    k_scan2<<<BB*CH, 256, 0, stream>>>(deltaG, xln, Bvp, Cvp, alog, Hin, dsk, g);
    k_glu<<<dim3(4, 512), 256, 0, stream>>>(g, Wt, gb, x, out);
}

// Round 17
// 105.170 us; speedup vs baseline: 2.4906x; 1.0209x over previous
//
#include <hip/hip_runtime.h>
#include <hip/hip_bf16.h>

#define BB 16
#define LL 2048
#define DD 256
#define NN 16
#define RR 16
#define CH 64
#define LC (LL/CH)   /* 32 */

static __device__ __forceinline__ float bf2f(unsigned short u) {
    return __uint_as_float(((unsigned)u) << 16);
}
static __device__ __forceinline__ unsigned short f2bf(float f) {
    unsigned u = __float_as_uint(f);
    u += 0x7FFFu + ((u >> 16) & 1u);
    return (unsigned short)(u >> 16);
}

typedef __attribute__((ext_vector_type(8))) short bf16x8;
typedef __attribute__((ext_vector_type(4))) short bf16x4;
typedef __attribute__((ext_vector_type(4))) float f32x4;

// al[n] = -exp(A_log)*log2(e), computed via exp2 (identical in all kernels)
static __device__ __forceinline__ float neg_exp_log2e(float a) {
    return -exp2f(a * 1.44269504f) * 1.44269504f;
}

// e[n] = E^(n+1), depth-4 product tree
static __device__ __forceinline__ void pow_tree(float E, float* e) {
    e[0] = E;
    e[1] = E * E;
    e[2] = e[1] * E;
    e[3] = e[1] * e[1];
    e[4] = e[3] * e[0];  e[5] = e[3] * e[1];  e[6] = e[3] * e[2];  e[7] = e[3] * e[3];
    e[8] = e[7] * e[0];  e[9] = e[7] * e[1];  e[10] = e[7] * e[2]; e[11] = e[7] * e[3];
    e[12] = e[7] * e[4]; e[13] = e[7] * e[5]; e[14] = e[7] * e[6]; e[15] = e[7] * e[7];
}

// ---------------------------------------------------------------------------
// prep: bid<16 -> Wxt (xw^T bf16, 48->64 pad); bid 16..143 -> Wt (glu_w^T);
// bid 144 -> Dwt (dtw^T, 256x32 bf16, K zero-padded 16->32)
// ---------------------------------------------------------------------------
__global__ __launch_bounds__(256) void k_prep(
    const float* __restrict__ xw, const float* __restrict__ gw,
    const float* __restrict__ dtw,
    unsigned short* __restrict__ Wxt, unsigned short* __restrict__ Wt,
    unsigned short* __restrict__ Dwt)
{
    __shared__ unsigned short s[32][33];
    const int bid = blockIdx.x;
    const int t = threadIdx.x;
    if (bid < 16) {
        const int idx = bid * 256 + t;
        const int n  = idx >> 6;
        const int k0 = (idx & 63) * 4;
        #pragma unroll
        for (int i = 0; i < 4; ++i) {
            float v = (n < 48) ? xw[(size_t)(k0 + i) * 48 + n] : 0.f;
            Wxt[(size_t)n * DD + k0 + i] = f2bf(v);
        }
    } else if (bid < 144) {
        const int bb = bid - 16;
        const int bx = bb & 15, by = bb >> 4;
        const int r = t >> 5, cc = t & 31;
        #pragma unroll
        for (int i = 0; i < 4; ++i)
            s[r + 8*i][cc] = f2bf(gw[(size_t)(by*32 + r + 8*i)*512 + bx*32 + cc]);
        __syncthreads();
        #pragma unroll
        for (int i = 0; i < 4; ++i)
            Wt[(size_t)(bx*32 + r + 8*i)*256 + by*32 + cc] = s[cc][r + 8*i];
    } else {
        unsigned short r32[32];
        #pragma unroll
        for (int k = 0; k < 16; ++k) r32[k] = f2bf(dtw[(size_t)k*DD + t]);
        #pragma unroll
        for (int k = 16; k < 32; ++k) r32[k] = 0;
        #pragma unroll
        for (int i = 0; i < 4; ++i)
            *(bf16x8*)&Dwt[(size_t)t*32 + i*8] = *(bf16x8*)&r32[i*8];
    }
}

// ---------------------------------------------------------------------------
// k_ln_scan1: LN -> x_proj MFMA -> dt_proj MFMA + softplus -> scan pass 1.
// LDS = 40960 B exactly -> 4 blocks/CU (single dispatch round, no tail).
// ---------------------------------------------------------------------------
template<bool FAST>
__device__ __forceinline__ void scan1_loop(
    const unsigned short (*sDel)[264], const unsigned short (*As)[264],
    const float (*sB)[20], const float* al, int t,
    float* h, float* dsum)
{
    #pragma unroll 4
    for (int l = 0; l < LC; ++l) {
        const float dl = bf2f(sDel[l][t]);
        const float xl = bf2f(As[l][t]);
        const float dx = dl * xl;
        *dsum += dl;
        float e[NN];
        if (FAST) pow_tree(exp2f(al[0]*dl), e);
        else {
            #pragma unroll
            for (int n = 0; n < NN; ++n) e[n] = exp2f(al[n]*dl);
        }
        const float4 B0 = *(const float4*)&sB[l][0];
        const float4 B1 = *(const float4*)&sB[l][4];
        const float4 B2 = *(const float4*)&sB[l][8];
        const float4 B3 = *(const float4*)&sB[l][12];
        const float bb[16] = {B0.x,B0.y,B0.z,B0.w, B1.x,B1.y,B1.z,B1.w,
                              B2.x,B2.y,B2.z,B2.w, B3.x,B3.y,B3.z,B3.w};
        #pragma unroll
        for (int n = 0; n < NN; ++n)
            h[n] = fmaf(e[n], h[n], dx * bb[n]);
    }
}

__global__ __launch_bounds__(256) void k_ln_scan1(
    const float* __restrict__ x,
    const float* __restrict__ ln_w,
    const float* __restrict__ ln_b,
    const unsigned short* __restrict__ Wxt,
    const unsigned short* __restrict__ Dwt,
    const float* __restrict__ dtb,
    const float* __restrict__ A_log,
    unsigned short* __restrict__ xln,
    unsigned short* __restrict__ delta,
    float* __restrict__ Bv,
    float* __restrict__ Cv,
    unsigned short* __restrict__ S,     // bf16
    float* __restrict__ Dsum)
{
    const int t = threadIdx.x;
    const int blk = blockIdx.x;
    const size_t m0 = (size_t)blk * LC;
    const int row = t >> 3, seg = t & 7;
    const size_t grow = m0 + row;

    __shared__ unsigned short As[LC][264];     // 16896 B
    __shared__ unsigned short sDel[LC][264];   // 16896 B
    __shared__ unsigned short sdt16[LC][40];   // 2560 B
    __shared__ float sB[LC][20];               // 2560 B
    __shared__ float slnw[256], slnb[256];     // 2048 B  (total 40960)

    // ---- stage ln_w/ln_b + zero-fill sdt16 K-pad columns
    {
        const int tt = t & 63;
        if (t < 64)       *(float4*)&slnw[tt*4] = *(const float4*)&ln_w[tt*4];
        else if (t < 128) *(float4*)&slnb[tt*4] = *(const float4*)&ln_b[tt*4];
        if (t < 64) {
            const bf16x8 z = {0,0,0,0,0,0,0,0};
            *(bf16x8*)&sdt16[t >> 1][16 + (t & 1)*8] = z;
        }
    }
    float al[NN];
    bool fast = true;
    #pragma unroll
    for (int n = 0; n < NN; ++n) {
        al[n] = neg_exp_log2e(A_log[t*NN + n]);
        fast = fast && (fabsf(al[n] - (n+1)*al[0]) <= 1e-3f*fabsf(al[n]) + 1e-6f);
    }

    // ---- LN (8 threads/row, 32 floats/thread, strided)
    float v[32];
    #pragma unroll
    for (int i = 0; i < 8; ++i)
        *(float4*)&v[i*4] = *(const float4*)(x + grow*DD + i*32 + seg*4);
    float s = 0.f, q = 0.f;
    #pragma unroll
    for (int i = 0; i < 32; ++i) { s += v[i]; q = fmaf(v[i], v[i], q); }
    #pragma unroll
    for (int o = 1; o < 8; o <<= 1) {
        s += __shfl_xor(s, o);
        q += __shfl_xor(q, o);
    }
    const float mu = s * (1.f/DD);
    const float rs = rsqrtf(q * (1.f/DD) - mu*mu + 1e-5f);
    __syncthreads();
    #pragma unroll
    for (int i = 0; i < 8; ++i) {
        const int c = i*32 + seg*4;
        const float4 wv = *(const float4*)&slnw[c];
        const float4 bv = *(const float4*)&slnb[c];
        unsigned short o16[4];
        o16[0] = f2bf((v[i*4+0]-mu)*rs*wv.x + bv.x);
        o16[1] = f2bf((v[i*4+1]-mu)*rs*wv.y + bv.y);
        o16[2] = f2bf((v[i*4+2]-mu)*rs*wv.z + bv.z);
        o16[3] = f2bf((v[i*4+3]-mu)*rs*wv.w + bv.w);
        *(bf16x4*)&xln[grow*DD + c] = *(bf16x4*)&o16[0];
        *(bf16x4*)&As[row][c]       = *(bf16x4*)&o16[0];
    }
    __syncthreads();

    const int w = t >> 6, lane = t & 63;
    const int cl = lane & 15, rq = lane >> 4;

    // ---- x_proj MFMA: (32x256)@(256x48) -> sdt16(bf16) | sB+Bv | Cv
    {
        const int mh = (w & 1) * 16;
        const int nh = (w >> 1) * 32;
        f32x4 acc0 = {0.f,0.f,0.f,0.f}, acc1 = {0.f,0.f,0.f,0.f};
        #pragma unroll
        for (int k0 = 0; k0 < 256; k0 += 32) {
            const bf16x8 a  = *(const bf16x8*)&As[mh + cl][k0 + rq*8];
            const bf16x8 b0 = *(const bf16x8*)&Wxt[(size_t)(nh + cl)*DD + k0 + rq*8];
            acc0 = __builtin_amdgcn_mfma_f32_16x16x32_bf16(a, b0, acc0, 0, 0, 0);
            if (w < 2) {
                const bf16x8 b1 = *(const bf16x8*)&Wxt[(size_t)(nh + 16 + cl)*DD + k0 + rq*8];
                acc1 = __builtin_amdgcn_mfma_f32_16x16x32_bf16(a, b1, acc1, 0, 0, 0);
            }
        }
        if (w < 2) {
            #pragma unroll
            for (int r = 0; r < 4; ++r) {
                const int rr = mh + rq*4 + r;
                sdt16[rr][cl] = f2bf(acc0[r]);
                sB[rr][cl]    = acc1[r];
                Bv[(m0 + rr)*NN + cl] = acc1[r];
            }
        } else {
            #pragma unroll
            for (int r = 0; r < 4; ++r)
                Cv[(m0 + mh + rq*4 + r)*NN + cl] = acc0[r];
        }
    }
    __syncthreads();

    // ---- dt_proj MFMA: (32x32K)@(32Kx256) -> softplus -> sDel + global delta
    {
        const int mh = (w & 1) * 16;
        const int nbase = (w >> 1) * 8;
        const bf16x8 a = *(const bf16x8*)&sdt16[mh + cl][rq*8];
        #pragma unroll
        for (int nt = 0; nt < 8; ++nt) {
            const int n0 = (nbase + nt) * 16;
            const bf16x8 b = *(const bf16x8*)&Dwt[(size_t)(n0 + cl)*32 + rq*8];
            f32x4 acc = {0.f,0.f,0.f,0.f};
            acc = __builtin_amdgcn_mfma_f32_16x16x32_bf16(a, b, acc, 0, 0, 0);
            const float bia = dtb[n0 + cl];
            #pragma unroll
            for (int r = 0; r < 4; ++r) {
                const float ac = acc[r] + bia;
                const float sp = (ac > 15.f) ? ac
                    : 0.69314718f * log2f(1.f + exp2f(ac * 1.44269504f));
                const unsigned short db = f2bf(sp);
                const int rr = mh + rq*4 + r;
                sDel[rr][n0 + cl] = db;
                delta[(m0 + rr)*DD + n0 + cl] = db;
            }
        }
    }
    __syncthreads();

    // ---- scan pass 1 (thread t = column d)
    float h[NN];
    #pragma unroll
    for (int n = 0; n < NN; ++n) h[n] = 0.f;
    float dsum = 0.f;
    if (fast) scan1_loop<true >(sDel, As, sB, al, t, h, &dsum);
    else      scan1_loop<false>(sDel, As, sB, al, t, h, &dsum);
    const size_t o = (size_t)blk * NN * DD + t;
    #pragma unroll
    for (int n = 0; n < NN; ++n) S[o + n*DD] = f2bf(h[n]);
    Dsum[(size_t)blk*DD + t] = dsum;
}

// ---------------------------------------------------------------------------
// combine: fold over 64 chunks -> Hin (bf16 in/out, fp32 accumulate)
// ---------------------------------------------------------------------------
__global__ __launch_bounds__(256) void k_combine(
    const unsigned short* __restrict__ S, const float* __restrict__ Dsum,
    const float* __restrict__ A_log, unsigned short* __restrict__ Hin)
{
    const int bi = blockIdx.x;
    const int d = threadIdx.x;
    const int n = bi & 15;
    const int b = bi >> 4;
    const float al = neg_exp_log2e(A_log[d*NN + n]);
    float h = 0.f;
    for (int c0 = 0; c0 < CH; c0 += 8) {
        float ds8[8];
        unsigned short s8[8];
        #pragma unroll
        for (int i = 0; i < 8; ++i) {
            const size_t blk = (size_t)b*CH + c0 + i;
            ds8[i] = Dsum[blk*DD + d];
            s8[i]  = S[(blk*NN + n)*DD + d];
        }
        #pragma unroll
        for (int i = 0; i < 8; ++i) {
            const size_t blk = (size_t)b*CH + c0 + i;
            Hin[(blk*NN + n)*DD + d] = f2bf(h);
            h = fmaf(exp2f(al * ds8[i]), h, bf2f(s8[i]));
        }
    }
}

// ---------------------------------------------------------------------------
// scan pass 2 — ZERO LDS: per-step coalesced global u16 reads (delta/xln,
// L3-resident) + wave-uniform float4 B/C reads (scalar/broadcast). The
// staging phase, barrier, and all ds_read traffic are gone; VMEM (20% busy)
// absorbs the load. Safe vs g-aliasing: each (row,d) is read->written by the
// same thread with a data dependence.
// ---------------------------------------------------------------------------
template<bool FAST>
__device__ __forceinline__ void scan2_loop(
    const unsigned short* __restrict__ delta,
    const unsigned short* __restrict__ xln,
    const float* __restrict__ Bv,
    const float* __restrict__ Cv,
    size_t rowbase, const float* al, int d, float* h, float dsk,
    unsigned short* __restrict__ g)
{
    #pragma unroll 4
    for (int l = 0; l < LC; ++l) {
        const size_t row = rowbase + l;
        const float dl = bf2f(delta[row*DD + d]);
        const float xl = bf2f(xln[row*DD + d]);
        const float dx = dl * xl;
        float e[NN];
        if (FAST) pow_tree(exp2f(al[0]*dl), e);
        else {
            #pragma unroll
            for (int n = 0; n < NN; ++n) e[n] = exp2f(al[n]*dl);
        }
        const float* Bp = Bv + row*NN;
        const float* Cp = Cv + row*NN;
        const float4 B0 = *(const float4*)(Bp + 0);
        const float4 B1 = *(const float4*)(Bp + 4);
        const float4 B2 = *(const float4*)(Bp + 8);
        const float4 B3 = *(const float4*)(Bp + 12);
        const float bb[16] = {B0.x,B0.y,B0.z,B0.w, B1.x,B1.y,B1.z,B1.w,
                              B2.x,B2.y,B2.z,B2.w, B3.x,B3.y,B3.z,B3.w};
        const float4 C0 = *(const float4*)(Cp + 0);
        const float4 C1 = *(const float4*)(Cp + 4);
        const float4 C2 = *(const float4*)(Cp + 8);
        const float4 C3 = *(const float4*)(Cp + 12);
        const float cc[16] = {C0.x,C0.y,C0.z,C0.w, C1.x,C1.y,C1.z,C1.w,
                              C2.x,C2.y,C2.z,C2.w, C3.x,C3.y,C3.z,C3.w};
        float yb[4] = {0.f, 0.f, 0.f, 0.f};
        #pragma unroll
        for (int n = 0; n < NN; ++n) {
            h[n] = fmaf(e[n], h[n], dx * bb[n]);
            yb[n & 3] = fmaf(h[n], cc[n], yb[n & 3]);
        }
        const float vv = (yb[0]+yb[1]) + (yb[2]+yb[3]) + xl * dsk;
        const float u  = 0.7978845608f * (vv + 0.044715f*vv*vv*vv);
        const float t2 = exp2f(2.8853900818f * u);
        const float th = 1.f - 2.f/(t2 + 1.f);
        g[row*DD + d] = f2bf(0.5f * vv * (1.f + th));
    }
}

__global__ __launch_bounds__(256) void k_scan2(
    const unsigned short* __restrict__ delta,
    const unsigned short* __restrict__ xln,
    const float* __restrict__ Bv,
    const float* __restrict__ Cv,
    const float* __restrict__ A_log,
    const unsigned short* __restrict__ Hin,   // bf16
    const float* __restrict__ Dskip,
    unsigned short* __restrict__ g)
{
    const int blk = blockIdx.x;
    const int c = blk & (CH-1);
    const int b = blk >> 6;
    const int d = threadIdx.x;
    const size_t rowbase = (size_t)b*LL + c*LC;

    float al[NN];
    bool fast = true;
    #pragma unroll
    for (int n = 0; n < NN; ++n) {
        al[n] = neg_exp_log2e(A_log[d*NN + n]);
        fast = fast && (fabsf(al[n] - (n+1)*al[0]) <= 1e-3f*fabsf(al[n]) + 1e-6f);
    }
    float h[NN];
    const size_t ob = (size_t)blk * NN * DD + d;
    #pragma unroll
    for (int n = 0; n < NN; ++n) h[n] = bf2f(Hin[ob + n*DD]);
    const float dsk = Dskip[d];
    if (fast) scan2_loop<true >(delta, xln, Bv, Cv, rowbase, al, d, h, dsk, g);
    else      scan2_loop<false>(delta, xln, Bv, Cv, rowbase, al, d, h, dsk, g);
}

// ---------------------------------------------------------------------------
// GLU GEMM (32768x256 @ 256x512) + bias + sigmoid gate + skip
// ---------------------------------------------------------------------------
__global__ __launch_bounds__(256) void k_glu(
    const unsigned short* __restrict__ g,
    const unsigned short* __restrict__ Wt,
    const float* __restrict__ gb,
    const float* __restrict__ x,
    float* __restrict__ out)
{
    __shared__ unsigned short As[64][40];
    __shared__ unsigned short Bl[64][40];
    __shared__ unsigned short Bh[64][40];
    const int n0 = blockIdx.x * 64;
    const int m0 = blockIdx.y * 64;
    const int t = threadIdx.x;
    const int w = t >> 6, lane = t & 63;
    const int r = t >> 2, q = t & 3;
    const int cl = lane & 15, rq = lane >> 4;
    f32x4 accL[4], accH[4];
    const f32x4 zz = {0.f, 0.f, 0.f, 0.f};
    #pragma unroll
    for (int nf = 0; nf < 4; ++nf) { accL[nf] = zz; accH[nf] = zz; }

    for (int k0 = 0; k0 < 256; k0 += 32) {
        *(bf16x8*)(&As[r][q*8]) = *(const bf16x8*)(&g [(size_t)(m0+r)*DD + k0 + q*8]);
        *(bf16x8*)(&Bl[r][q*8]) = *(const bf16x8*)(&Wt[(size_t)(n0+r)*DD + k0 + q*8]);
        *(bf16x8*)(&Bh[r][q*8]) = *(const bf16x8*)(&Wt[(size_t)(n0+256+r)*DD + k0 + q*8]);
        __syncthreads();
        const bf16x8 a = *(const bf16x8*)(&As[w*16 + cl][rq*8]);
        #pragma unroll
        for (int nf = 0; nf < 4; ++nf) {
            const bf16x8 bl = *(const bf16x8*)(&Bl[nf*16 + cl][rq*8]);
            const bf16x8 bh = *(const bf16x8*)(&Bh[nf*16 + cl][rq*8]);
            accL[nf] = __builtin_amdgcn_mfma_f32_16x16x32_bf16(a, bl, accL[nf], 0, 0, 0);
            accH[nf] = __builtin_amdgcn_mfma_f32_16x16x32_bf16(a, bh, accH[nf], 0, 0, 0);
        }
        __syncthreads();
    }
    #pragma unroll
    for (int nf = 0; nf < 4; ++nf) {
        const int j = n0 + nf*16 + cl;
        const float bL = gb[j];
        const float bH = gb[j + 256];
        #pragma unroll
        for (int rr = 0; rr < 4; ++rr) {
            const int m = m0 + w*16 + rq*4 + rr;
            const float lo = accL[nf][rr] + bL;
            const float hi = accH[nf][rr] + bH;
            const float sg = 1.f / (1.f + exp2f(-1.44269504f * hi));
            out[(size_t)m*DD + j] = lo * sg + x[(size_t)m*DD + j];
        }
    }
}

extern "C" void kernel_launch(void* const* d_in, const int* in_sizes, int n_in,
                              void* d_out, int out_size, void* d_ws, size_t ws_size,
                              hipStream_t stream)
{
    const float* x    = (const float*)d_in[0];
    const float* ln_w = (const float*)d_in[1];
    const float* ln_b = (const float*)d_in[2];
    const float* xpw  = (const float*)d_in[3];
    const float* dtw  = (const float*)d_in[4];
    const float* dtb  = (const float*)d_in[5];
    const float* alog = (const float*)d_in[6];
    const float* dsk  = (const float*)d_in[7];
    const float* gw   = (const float*)d_in[8];
    const float* gb   = (const float*)d_in[9];
    float* out = (float*)d_out;

    char* ws = (char*)d_ws;
    size_t off = 0;
    auto alloc = [&](size_t bytes) {
        char* p = ws + off; off += (bytes + 255) & ~(size_t)255; return p;
    };
    unsigned short* xln    = (unsigned short*)alloc((size_t)BB*LL*DD*2);
    unsigned short* deltaG = (unsigned short*)alloc((size_t)BB*LL*DD*2);
    float*          Bvp    = (float*)         alloc((size_t)BB*LL*NN*4);
    float*          Cvp    = (float*)         alloc((size_t)BB*LL*NN*4);
    unsigned short* S      = (unsigned short*)alloc((size_t)BB*CH*NN*DD*2);
    float*          Dsum   = (float*)         alloc((size_t)BB*CH*DD*4);
    unsigned short* Hin    = (unsigned short*)alloc((size_t)BB*CH*NN*DD*2);
    unsigned short* Wt     = (unsigned short*)alloc((size_t)512*256*2);
    unsigned short* Wxt    = (unsigned short*)alloc((size_t)64*256*2);
    unsigned short* Dwt    = (unsigned short*)alloc((size_t)256*32*2);
    unsigned short* g      = deltaG;   // scan2 overwrites delta in place

    k_prep<<<145, 256, 0, stream>>>(xpw, gw, dtw, Wxt, Wt, Dwt);
    k_ln_scan1<<<BB*CH, 256, 0, stream>>>(x, ln_w, ln_b, Wxt, Dwt, dtb, alog,
                                          xln, deltaG, Bvp, Cvp, S, Dsum);
    k_combine<<<256, 256, 0, stream>>>(S, Dsum, alog, Hin);
    k_scan2<<<BB*CH, 256, 0, stream>>>(deltaG, xln, Bvp, Cvp, alog, Hin, dsk, g);
    k_glu<<<dim3(4, 512), 256, 0, stream>>>(g, Wt, gb, x, out);
}

// Round 18
// 104.805 us; speedup vs baseline: 2.4993x; 1.0035x over previous
//
#include <hip/hip_runtime.h>
#include <hip/hip_bf16.h>

#define BB 16
#define LL 2048
#define DD 256
#define NN 16
#define RR 16
#define CH 64
#define LC (LL/CH)   /* 32 */

static __device__ __forceinline__ float bf2f(unsigned short u) {
    return __uint_as_float(((unsigned)u) << 16);
}
static __device__ __forceinline__ unsigned short f2bf(float f) {
    unsigned u = __float_as_uint(f);
    u += 0x7FFFu + ((u >> 16) & 1u);
    return (unsigned short)(u >> 16);
}

typedef __attribute__((ext_vector_type(8))) short bf16x8;
typedef __attribute__((ext_vector_type(4))) short bf16x4;
typedef __attribute__((ext_vector_type(4))) float f32x4;

// al[n] = -exp(A_log)*log2(e), computed via exp2 (identical in all kernels)
static __device__ __forceinline__ float neg_exp_log2e(float a) {
    return -exp2f(a * 1.44269504f) * 1.44269504f;
}

// e[n] = E^(n+1), depth-4 product tree
static __device__ __forceinline__ void pow_tree(float E, float* e) {
    e[0] = E;
    e[1] = E * E;
    e[2] = e[1] * E;
    e[3] = e[1] * e[1];
    e[4] = e[3] * e[0];  e[5] = e[3] * e[1];  e[6] = e[3] * e[2];  e[7] = e[3] * e[3];
    e[8] = e[7] * e[0];  e[9] = e[7] * e[1];  e[10] = e[7] * e[2]; e[11] = e[7] * e[3];
    e[12] = e[7] * e[4]; e[13] = e[7] * e[5]; e[14] = e[7] * e[6]; e[15] = e[7] * e[7];
}

// ---------------------------------------------------------------------------
// prep: bid<16 -> Wxt (xw^T bf16, 48->64 pad); bid 16..143 -> Wt (glu_w^T);
// bid 144 -> Dwt (dtw^T, 256x32 bf16, K zero-padded 16->32)
// ---------------------------------------------------------------------------
__global__ __launch_bounds__(256) void k_prep(
    const float* __restrict__ xw, const float* __restrict__ gw,
    const float* __restrict__ dtw,
    unsigned short* __restrict__ Wxt, unsigned short* __restrict__ Wt,
    unsigned short* __restrict__ Dwt)
{
    __shared__ unsigned short s[32][33];
    const int bid = blockIdx.x;
    const int t = threadIdx.x;
    if (bid < 16) {
        const int idx = bid * 256 + t;
        const int n  = idx >> 6;
        const int k0 = (idx & 63) * 4;
        #pragma unroll
        for (int i = 0; i < 4; ++i) {
            float v = (n < 48) ? xw[(size_t)(k0 + i) * 48 + n] : 0.f;
            Wxt[(size_t)n * DD + k0 + i] = f2bf(v);
        }
    } else if (bid < 144) {
        const int bb = bid - 16;
        const int bx = bb & 15, by = bb >> 4;
        const int r = t >> 5, cc = t & 31;
        #pragma unroll
        for (int i = 0; i < 4; ++i)
            s[r + 8*i][cc] = f2bf(gw[(size_t)(by*32 + r + 8*i)*512 + bx*32 + cc]);
        __syncthreads();
        #pragma unroll
        for (int i = 0; i < 4; ++i)
            Wt[(size_t)(bx*32 + r + 8*i)*256 + by*32 + cc] = s[cc][r + 8*i];
    } else {
        unsigned short r32[32];
        #pragma unroll
        for (int k = 0; k < 16; ++k) r32[k] = f2bf(dtw[(size_t)k*DD + t]);
        #pragma unroll
        for (int k = 16; k < 32; ++k) r32[k] = 0;
        #pragma unroll
        for (int i = 0; i < 4; ++i)
            *(bf16x8*)&Dwt[(size_t)t*32 + i*8] = *(bf16x8*)&r32[i*8];
    }
}

// ---------------------------------------------------------------------------
// k_ln_scan1: LN -> x_proj MFMA -> dt_proj MFMA + softplus -> scan pass 1.
// LDS = 40960 B exactly -> 4 blocks/CU.
// ---------------------------------------------------------------------------
template<bool FAST>
__device__ __forceinline__ void scan1_loop(
    const unsigned short (*sDel)[264], const unsigned short (*As)[264],
    const float (*sB)[20], const float* al, int t,
    float* h, float* dsum)
{
    #pragma unroll 4
    for (int l = 0; l < LC; ++l) {
        const float dl = bf2f(sDel[l][t]);
        const float xl = bf2f(As[l][t]);
        const float dx = dl * xl;
        *dsum += dl;
        float e[NN];
        if (FAST) pow_tree(exp2f(al[0]*dl), e);
        else {
            #pragma unroll
            for (int n = 0; n < NN; ++n) e[n] = exp2f(al[n]*dl);
        }
        const float4 B0 = *(const float4*)&sB[l][0];
        const float4 B1 = *(const float4*)&sB[l][4];
        const float4 B2 = *(const float4*)&sB[l][8];
        const float4 B3 = *(const float4*)&sB[l][12];
        const float bb[16] = {B0.x,B0.y,B0.z,B0.w, B1.x,B1.y,B1.z,B1.w,
                              B2.x,B2.y,B2.z,B2.w, B3.x,B3.y,B3.z,B3.w};
        #pragma unroll
        for (int n = 0; n < NN; ++n)
            h[n] = fmaf(e[n], h[n], dx * bb[n]);
    }
}

__global__ __launch_bounds__(256) void k_ln_scan1(
    const float* __restrict__ x,
    const float* __restrict__ ln_w,
    const float* __restrict__ ln_b,
    const unsigned short* __restrict__ Wxt,
    const unsigned short* __restrict__ Dwt,
    const float* __restrict__ dtb,
    const float* __restrict__ A_log,
    unsigned short* __restrict__ xln,
    unsigned short* __restrict__ delta,
    float* __restrict__ Bv,
    float* __restrict__ Cv,
    unsigned short* __restrict__ S,     // bf16
    float* __restrict__ Dsum)
{
    const int t = threadIdx.x;
    const int blk = blockIdx.x;
    const size_t m0 = (size_t)blk * LC;
    const int row = t >> 3, seg = t & 7;
    const size_t grow = m0 + row;

    __shared__ unsigned short As[LC][264];     // 16896 B
    __shared__ unsigned short sDel[LC][264];   // 16896 B
    __shared__ unsigned short sdt16[LC][40];   // 2560 B
    __shared__ float sB[LC][20];               // 2560 B
    __shared__ float slnw[256], slnb[256];     // 2048 B  (total 40960)

    {
        const int tt = t & 63;
        if (t < 64)       *(float4*)&slnw[tt*4] = *(const float4*)&ln_w[tt*4];
        else if (t < 128) *(float4*)&slnb[tt*4] = *(const float4*)&ln_b[tt*4];
        if (t < 64) {
            const bf16x8 z = {0,0,0,0,0,0,0,0};
            *(bf16x8*)&sdt16[t >> 1][16 + (t & 1)*8] = z;
        }
    }
    float al[NN];
    bool fast = true;
    #pragma unroll
    for (int n = 0; n < NN; ++n) {
        al[n] = neg_exp_log2e(A_log[t*NN + n]);
        fast = fast && (fabsf(al[n] - (n+1)*al[0]) <= 1e-3f*fabsf(al[n]) + 1e-6f);
    }

    float v[32];
    #pragma unroll
    for (int i = 0; i < 8; ++i)
        *(float4*)&v[i*4] = *(const float4*)(x + grow*DD + i*32 + seg*4);
    float s = 0.f, q = 0.f;
    #pragma unroll
    for (int i = 0; i < 32; ++i) { s += v[i]; q = fmaf(v[i], v[i], q); }
    #pragma unroll
    for (int o = 1; o < 8; o <<= 1) {
        s += __shfl_xor(s, o);
        q += __shfl_xor(q, o);
    }
    const float mu = s * (1.f/DD);
    const float rs = rsqrtf(q * (1.f/DD) - mu*mu + 1e-5f);
    __syncthreads();
    #pragma unroll
    for (int i = 0; i < 8; ++i) {
        const int c = i*32 + seg*4;
        const float4 wv = *(const float4*)&slnw[c];
        const float4 bv = *(const float4*)&slnb[c];
        unsigned short o16[4];
        o16[0] = f2bf((v[i*4+0]-mu)*rs*wv.x + bv.x);
        o16[1] = f2bf((v[i*4+1]-mu)*rs*wv.y + bv.y);
        o16[2] = f2bf((v[i*4+2]-mu)*rs*wv.z + bv.z);
        o16[3] = f2bf((v[i*4+3]-mu)*rs*wv.w + bv.w);
        *(bf16x4*)&xln[grow*DD + c] = *(bf16x4*)&o16[0];
        *(bf16x4*)&As[row][c]       = *(bf16x4*)&o16[0];
    }
    __syncthreads();

    const int w = t >> 6, lane = t & 63;
    const int cl = lane & 15, rq = lane >> 4;

    {
        const int mh = (w & 1) * 16;
        const int nh = (w >> 1) * 32;
        f32x4 acc0 = {0.f,0.f,0.f,0.f}, acc1 = {0.f,0.f,0.f,0.f};
        #pragma unroll
        for (int k0 = 0; k0 < 256; k0 += 32) {
            const bf16x8 a  = *(const bf16x8*)&As[mh + cl][k0 + rq*8];
            const bf16x8 b0 = *(const bf16x8*)&Wxt[(size_t)(nh + cl)*DD + k0 + rq*8];
            acc0 = __builtin_amdgcn_mfma_f32_16x16x32_bf16(a, b0, acc0, 0, 0, 0);
            if (w < 2) {
                const bf16x8 b1 = *(const bf16x8*)&Wxt[(size_t)(nh + 16 + cl)*DD + k0 + rq*8];
                acc1 = __builtin_amdgcn_mfma_f32_16x16x32_bf16(a, b1, acc1, 0, 0, 0);
            }
        }
        if (w < 2) {
            #pragma unroll
            for (int r = 0; r < 4; ++r) {
                const int rr = mh + rq*4 + r;
                sdt16[rr][cl] = f2bf(acc0[r]);
                sB[rr][cl]    = acc1[r];
                Bv[(m0 + rr)*NN + cl] = acc1[r];
            }
        } else {
            #pragma unroll
            for (int r = 0; r < 4; ++r)
                Cv[(m0 + mh + rq*4 + r)*NN + cl] = acc0[r];
        }
    }
    __syncthreads();

    {
        const int mh = (w & 1) * 16;
        const int nbase = (w >> 1) * 8;
        const bf16x8 a = *(const bf16x8*)&sdt16[mh + cl][rq*8];
        #pragma unroll
        for (int nt = 0; nt < 8; ++nt) {
            const int n0 = (nbase + nt) * 16;
            const bf16x8 b = *(const bf16x8*)&Dwt[(size_t)(n0 + cl)*32 + rq*8];
            f32x4 acc = {0.f,0.f,0.f,0.f};
            acc = __builtin_amdgcn_mfma_f32_16x16x32_bf16(a, b, acc, 0, 0, 0);
            const float bia = dtb[n0 + cl];
            #pragma unroll
            for (int r = 0; r < 4; ++r) {
                const float ac = acc[r] + bia;
                const float sp = (ac > 15.f) ? ac
                    : 0.69314718f * log2f(1.f + exp2f(ac * 1.44269504f));
                const unsigned short db = f2bf(sp);
                const int rr = mh + rq*4 + r;
                sDel[rr][n0 + cl] = db;
                delta[(m0 + rr)*DD + n0 + cl] = db;
            }
        }
    }
    __syncthreads();

    float h[NN];
    #pragma unroll
    for (int n = 0; n < NN; ++n) h[n] = 0.f;
    float dsum = 0.f;
    if (fast) scan1_loop<true >(sDel, As, sB, al, t, h, &dsum);
    else      scan1_loop<false>(sDel, As, sB, al, t, h, &dsum);
    const size_t o = (size_t)blk * NN * DD + t;
    #pragma unroll
    for (int n = 0; n < NN; ++n) S[o + n*DD] = f2bf(h[n]);
    Dsum[(size_t)blk*DD + t] = dsum;
}

// ---------------------------------------------------------------------------
// combine: fold over 64 chunks -> Hin (bf16 in/out, fp32 accumulate)
// ---------------------------------------------------------------------------
__global__ __launch_bounds__(256) void k_combine(
    const unsigned short* __restrict__ S, const float* __restrict__ Dsum,
    const float* __restrict__ A_log, unsigned short* __restrict__ Hin)
{
    const int bi = blockIdx.x;
    const int d = threadIdx.x;
    const int n = bi & 15;
    const int b = bi >> 4;
    const float al = neg_exp_log2e(A_log[d*NN + n]);
    float h = 0.f;
    for (int c0 = 0; c0 < CH; c0 += 8) {
        float ds8[8];
        unsigned short s8[8];
        #pragma unroll
        for (int i = 0; i < 8; ++i) {
            const size_t blk = (size_t)b*CH + c0 + i;
            ds8[i] = Dsum[blk*DD + d];
            s8[i]  = S[(blk*NN + n)*DD + d];
        }
        #pragma unroll
        for (int i = 0; i < 8; ++i) {
            const size_t blk = (size_t)b*CH + c0 + i;
            Hin[(blk*NN + n)*DD + d] = f2bf(h);
            h = fmaf(exp2f(al * ds8[i]), h, bf2f(s8[i]));
        }
    }
}

// ---------------------------------------------------------------------------
// scan pass 2 — zero LDS, direct global reads (L3-resident, coalesced)
// ---------------------------------------------------------------------------
template<bool FAST>
__device__ __forceinline__ void scan2_loop(
    const unsigned short* __restrict__ delta,
    const unsigned short* __restrict__ xln,
    const float* __restrict__ Bv,
    const float* __restrict__ Cv,
    size_t rowbase, const float* al, int d, float* h, float dsk,
    unsigned short* __restrict__ g)
{
    #pragma unroll 4
    for (int l = 0; l < LC; ++l) {
        const size_t row = rowbase + l;
        const float dl = bf2f(delta[row*DD + d]);
        const float xl = bf2f(xln[row*DD + d]);
        const float dx = dl * xl;
        float e[NN];
        if (FAST) pow_tree(exp2f(al[0]*dl), e);
        else {
            #pragma unroll
            for (int n = 0; n < NN; ++n) e[n] = exp2f(al[n]*dl);
        }
        const float* Bp = Bv + row*NN;
        const float* Cp = Cv + row*NN;
        const float4 B0 = *(const float4*)(Bp + 0);
        const float4 B1 = *(const float4*)(Bp + 4);
        const float4 B2 = *(const float4*)(Bp + 8);
        const float4 B3 = *(const float4*)(Bp + 12);
        const float bb[16] = {B0.x,B0.y,B0.z,B0.w, B1.x,B1.y,B1.z,B1.w,
                              B2.x,B2.y,B2.z,B2.w, B3.x,B3.y,B3.z,B3.w};
        const float4 C0 = *(const float4*)(Cp + 0);
        const float4 C1 = *(const float4*)(Cp + 4);
        const float4 C2 = *(const float4*)(Cp + 8);
        const float4 C3 = *(const float4*)(Cp + 12);
        const float cc[16] = {C0.x,C0.y,C0.z,C0.w, C1.x,C1.y,C1.z,C1.w,
                              C2.x,C2.y,C2.z,C2.w, C3.x,C3.y,C3.z,C3.w};
        float yb[4] = {0.f, 0.f, 0.f, 0.f};
        #pragma unroll
        for (int n = 0; n < NN; ++n) {
            h[n] = fmaf(e[n], h[n], dx * bb[n]);
            yb[n & 3] = fmaf(h[n], cc[n], yb[n & 3]);
        }
        const float vv = (yb[0]+yb[1]) + (yb[2]+yb[3]) + xl * dsk;
        const float u  = 0.7978845608f * (vv + 0.044715f*vv*vv*vv);
        const float t2 = exp2f(2.8853900818f * u);
        const float th = 1.f - 2.f/(t2 + 1.f);
        g[row*DD + d] = f2bf(0.5f * vv * (1.f + th));
    }
}

__global__ __launch_bounds__(256) void k_scan2(
    const unsigned short* __restrict__ delta,
    const unsigned short* __restrict__ xln,
    const float* __restrict__ Bv,
    const float* __restrict__ Cv,
    const float* __restrict__ A_log,
    const unsigned short* __restrict__ Hin,   // bf16
    const float* __restrict__ Dskip,
    unsigned short* __restrict__ g)
{
    const int blk = blockIdx.x;
    const int c = blk & (CH-1);
    const int b = blk >> 6;
    const int d = threadIdx.x;
    const size_t rowbase = (size_t)b*LL + c*LC;

    float al[NN];
    bool fast = true;
    #pragma unroll
    for (int n = 0; n < NN; ++n) {
        al[n] = neg_exp_log2e(A_log[d*NN + n]);
        fast = fast && (fabsf(al[n] - (n+1)*al[0]) <= 1e-3f*fabsf(al[n]) + 1e-6f);
    }
    float h[NN];
    const size_t ob = (size_t)blk * NN * DD + d;
    #pragma unroll
    for (int n = 0; n < NN; ++n) h[n] = bf2f(Hin[ob + n*DD]);
    const float dsk = Dskip[d];
    if (fast) scan2_loop<true >(delta, xln, Bv, Cv, rowbase, al, d, h, dsk, g);
    else      scan2_loop<false>(delta, xln, Bv, Cv, rowbase, al, d, h, dsk, g);
}

// ---------------------------------------------------------------------------
// GLU GEMM (32768x256 @ 256x512) + bias + sigmoid gate + skip
// M-tile 128 (was 64): halves Wt L2 re-reads; each staged B-frag feeds 2
// A-frags (16 MFMA/wave/k-step). Grid (4, 256). LDS 20.5 KB.
// ---------------------------------------------------------------------------
__global__ __launch_bounds__(256) void k_glu(
    const unsigned short* __restrict__ g,
    const unsigned short* __restrict__ Wt,
    const float* __restrict__ gb,
    const float* __restrict__ x,
    float* __restrict__ out)
{
    __shared__ unsigned short As[128][40];
    __shared__ unsigned short Bl[64][40];
    __shared__ unsigned short Bh[64][40];
    const int n0 = blockIdx.x * 64;
    const int m0 = blockIdx.y * 128;
    const int t = threadIdx.x;
    const int w = t >> 6, lane = t & 63;
    const int cl = lane & 15, rq = lane >> 4;
    const int ra = t >> 1, qa = t & 1;          // As staging: 2 thr/row, 16 cols each
    const int rb = t >> 2, qb = (t & 3) * 8;    // B staging: 4 thr/row, 8 cols each
    f32x4 accL0[4], accL1[4], accH0[4], accH1[4];
    const f32x4 zz = {0.f, 0.f, 0.f, 0.f};
    #pragma unroll
    for (int nf = 0; nf < 4; ++nf) {
        accL0[nf] = zz; accL1[nf] = zz; accH0[nf] = zz; accH1[nf] = zz;
    }

    for (int k0 = 0; k0 < 256; k0 += 32) {
        *(bf16x8*)(&As[ra][qa*16 + 0]) = *(const bf16x8*)(&g[(size_t)(m0+ra)*DD + k0 + qa*16 + 0]);
        *(bf16x8*)(&As[ra][qa*16 + 8]) = *(const bf16x8*)(&g[(size_t)(m0+ra)*DD + k0 + qa*16 + 8]);
        *(bf16x8*)(&Bl[rb][qb]) = *(const bf16x8*)(&Wt[(size_t)(n0+rb)*DD + k0 + qb]);
        *(bf16x8*)(&Bh[rb][qb]) = *(const bf16x8*)(&Wt[(size_t)(n0+256+rb)*DD + k0 + qb]);
        __syncthreads();
        const bf16x8 a0 = *(const bf16x8*)(&As[w*32 + cl][rq*8]);
        const bf16x8 a1 = *(const bf16x8*)(&As[w*32 + 16 + cl][rq*8]);
        #pragma unroll
        for (int nf = 0; nf < 4; ++nf) {
            const bf16x8 bl = *(const bf16x8*)(&Bl[nf*16 + cl][rq*8]);
            const bf16x8 bh = *(const bf16x8*)(&Bh[nf*16 + cl][rq*8]);
            accL0[nf] = __builtin_amdgcn_mfma_f32_16x16x32_bf16(a0, bl, accL0[nf], 0, 0, 0);
            accL1[nf] = __builtin_amdgcn_mfma_f32_16x16x32_bf16(a1, bl, accL1[nf], 0, 0, 0);
            accH0[nf] = __builtin_amdgcn_mfma_f32_16x16x32_bf16(a0, bh, accH0[nf], 0, 0, 0);
            accH1[nf] = __builtin_amdgcn_mfma_f32_16x16x32_bf16(a1, bh, accH1[nf], 0, 0, 0);
        }
        __syncthreads();
    }
    #pragma unroll
    for (int nf = 0; nf < 4; ++nf) {
        const int j = n0 + nf*16 + cl;
        const float bL = gb[j];
        const float bH = gb[j + 256];
        #pragma unroll
        for (int rr = 0; rr < 4; ++rr) {
            {   // rows m0 + w*32 + 0..15
                const int m = m0 + w*32 + rq*4 + rr;
                const float lo = accL0[nf][rr] + bL;
                const float hi = accH0[nf][rr] + bH;
                const float sg = 1.f / (1.f + exp2f(-1.44269504f * hi));
                out[(size_t)m*DD + j] = lo * sg + x[(size_t)m*DD + j];
            }
            {   // rows m0 + w*32 + 16..31
                const int m = m0 + w*32 + 16 + rq*4 + rr;
                const float lo = accL1[nf][rr] + bL;
                const float hi = accH1[nf][rr] + bH;
                const float sg = 1.f / (1.f + exp2f(-1.44269504f * hi));
                out[(size_t)m*DD + j] = lo * sg + x[(size_t)m*DD + j];
            }
        }
    }
}

extern "C" void kernel_launch(void* const* d_in, const int* in_sizes, int n_in,
                              void* d_out, int out_size, void* d_ws, size_t ws_size,
                              hipStream_t stream)
{
    const float* x    = (const float*)d_in[0];
    const float* ln_w = (const float*)d_in[1];
    const float* ln_b = (const float*)d_in[2];
    const float* xpw  = (const float*)d_in[3];
    const float* dtw  = (const float*)d_in[4];
    const float* dtb  = (const float*)d_in[5];
    const float* alog = (const float*)d_in[6];
    const float* dsk  = (const float*)d_in[7];
    const float* gw   = (const float*)d_in[8];
    const float* gb   = (const float*)d_in[9];
    float* out = (float*)d_out;

    char* ws = (char*)d_ws;
    size_t off = 0;
    auto alloc = [&](size_t bytes) {
        char* p = ws + off; off += (bytes + 255) & ~(size_t)255; return p;
    };
    unsigned short* xln    = (unsigned short*)alloc((size_t)BB*LL*DD*2);
    unsigned short* deltaG = (unsigned short*)alloc((size_t)BB*LL*DD*2);
    float*          Bvp    = (float*)         alloc((size_t)BB*LL*NN*4);
    float*          Cvp    = (float*)         alloc((size_t)BB*LL*NN*4);
    unsigned short* S      = (unsigned short*)alloc((size_t)BB*CH*NN*DD*2);
    float*          Dsum   = (float*)         alloc((size_t)BB*CH*DD*4);
    unsigned short* Hin    = (unsigned short*)alloc((size_t)BB*CH*NN*DD*2);
    unsigned short* Wt     = (unsigned short*)alloc((size_t)512*256*2);
    unsigned short* Wxt    = (unsigned short*)alloc((size_t)64*256*2);
    unsigned short* Dwt    = (unsigned short*)alloc((size_t)256*32*2);
    unsigned short* g      = deltaG;   // scan2 overwrites delta in place

    k_prep<<<145, 256, 0, stream>>>(xpw, gw, dtw, Wxt, Wt, Dwt);
    k_ln_scan1<<<BB*CH, 256, 0, stream>>>(x, ln_w, ln_b, Wxt, Dwt, dtb, alog,
                                          xln, deltaG, Bvp, Cvp, S, Dsum);
    k_combine<<<256, 256, 0, stream>>>(S, Dsum, alog, Hin);
    k_scan2<<<BB*CH, 256, 0, stream>>>(deltaG, xln, Bvp, Cvp, alog, Hin, dsk, g);
    k_glu<<<dim3(4, 256), 256, 0, stream>>>(g, Wt, gb, x, out);
}